// Round 6
// baseline (282.762 us; speedup 1.0000x reference)
//
#include <hip/hip_runtime.h>

#define NB 262144
#define NNODE (NB * 4)
#define EMB_ELEMS ((size_t)NNODE * 64)

typedef __attribute__((ext_vector_type(8))) _Float16 f16x8;
typedef __attribute__((ext_vector_type(4))) float f32x4;
typedef __attribute__((ext_vector_type(4))) unsigned int u32x4;

// ---- weight-image layout (bytes), strides padded to 16B multiples ----
#define OW1E  0        // [128][40] f16 : W1^T ext (k0..3=W1, k4=b1, pad 0)
#define OW2T  10240    // [64][136] f16 : W2^T  (row jo, col ji)
#define OW3T  27648    // [64][72]  f16 : W3^T  (row h,  col j)
#define OW3GT 36864    // [32][72]  f16 : (W3@Wg1)^T (row e, col j)
#define OF32  41472    // f32 section
#define IMG_BYTES 42880
// f32 section offsets (floats)
#define FB2   0
#define FB3   64
#define FB3G  128
#define FBG1  160
#define FWG2  192      // [32][4]
#define FBG2  320
#define FAHAT 324      // [4][4]

#define NWAVE 8                                 // 512 threads
#define TRN_BYTES (NWAVE * 4096)                // per-wave 4KB transpose buffers
#define SMEM_BYTES (IMG_BYTES + TRN_BYTES)      // 75648 B -> 2 blocks/CU, 4 waves/SIMD

template <int J>
__device__ __forceinline__ float qb(float v) {      // broadcast quad-lane J (DPP)
    constexpr int ctrl = J | (J << 2) | (J << 4) | (J << 6);
    int r = __builtin_amdgcn_update_dpp(0, __builtin_bit_cast(int, v), ctrl, 0xF, 0xF, true);
    return __builtin_bit_cast(float, r);
}

// ---------------------------------------------------------------------------
// Kernel 1: adjacency union. One thread per NODE (coalesced float4 loads);
// quad lanes = one sample's 4 nodes; dots via DPP quad broadcasts.
// All DPP broadcasts at FULL exec before any divergent branch (R4 bug).
// ---------------------------------------------------------------------------
__global__ __launch_bounds__(256) void adj_kernel(const float* __restrict__ x,
                                                  unsigned int* __restrict__ mask_out) {
    __shared__ unsigned int smask;
    if (threadIdx.x == 0) smask = 0u;
    __syncthreads();

    const int t = blockIdx.x * 256 + threadIdx.x;   // node id (grid exact)
    const int c = t & 3;
    f32x4 v = *(const f32x4*)(x + (size_t)t * 4);
    float nn = sqrtf(v.x * v.x + v.y * v.y + v.z * v.z + v.w * v.w);
    float inv = 1.0f / fmaxf(nn, 1e-8f);

    unsigned int m = 0u;
#define DOTJ(J) do {                                                            \
        const float bx = qb<J>(v.x), by = qb<J>(v.y);                           \
        const float bz = qb<J>(v.z), bw = qb<J>(v.w);                           \
        const float bi = qb<J>(inv);     /* unconditional: full exec mask */    \
        const float d = v.x * bx + v.y * by + v.z * bz + v.w * bw;              \
        if ((int)((J) != c) & (int)(d * inv * bi > 0.5f)) {                     \
            const int i_ = c < (J) ? c : (J);                                   \
            const int j_ = c < (J) ? (J) : c;                                   \
            m |= 1u << (2 * i_ + j_ - 1 - (i_ >> 1));                           \
        }                                                                       \
    } while (0)
    DOTJ(0); DOTJ(1); DOTJ(2); DOTJ(3);
#undef DOTJ

    if (m) atomicOr(&smask, m);
    __syncthreads();
    if (threadIdx.x == 0 && smask) atomicOr(mask_out, smask);
}

// ---------------------------------------------------------------------------
// Kernel 2: build f16 weight image + f32 biases/Ahat in workspace.
// ---------------------------------------------------------------------------
__global__ __launch_bounds__(256) void prep_kernel(
    const float* __restrict__ W1, const float* __restrict__ b1,
    const float* __restrict__ W2, const float* __restrict__ b2,
    const float* __restrict__ W3, const float* __restrict__ b3,
    const float* __restrict__ Wg1, const float* __restrict__ bg1,
    const float* __restrict__ Wg2, const float* __restrict__ bg2,
    const unsigned int* __restrict__ mask_in, char* __restrict__ img)
{
    const int t = threadIdx.x;
    _Float16* H = (_Float16*)img;
    float* F = (float*)(img + OF32);

    for (int i = t; i < 128 * 40; i += 256) {           // W1E
        int j = i / 40, kk = i % 40;
        float v = (kk < 4) ? W1[kk * 128 + j] : (kk == 4 ? b1[j] : 0.f);
        H[OW1E / 2 + i] = (_Float16)v;
    }
    for (int i = t; i < 64 * 136; i += 256) {           // W2T
        int jo = i / 136, ji = i % 136;
        H[OW2T / 2 + i] = (_Float16)(ji < 128 ? W2[ji * 64 + jo] : 0.f);
    }
    for (int i = t; i < 64 * 72; i += 256) {            // W3T
        int h = i / 72, j = i % 72;
        H[OW3T / 2 + i] = (_Float16)(j < 64 ? W3[j * 64 + h] : 0.f);
    }
    for (int i = t; i < 32 * 72; i += 256) {            // W3GT = (W3@Wg1)^T
        int e = i / 72, j = i % 72;
        float s = 0.f;
        if (j < 64)
            for (int h = 0; h < 64; ++h) s = fmaf(W3[j * 64 + h], Wg1[h * 32 + e], s);
        H[OW3GT / 2 + i] = (_Float16)s;
    }
    for (int i = t; i < 64; i += 256) F[FB2 + i] = b2[i];
    for (int i = t; i < 64; i += 256) F[FB3 + i] = b3[i];
    for (int i = t; i < 32; i += 256) {                 // b3g = b3 @ Wg1
        float s = 0.f;
        for (int h = 0; h < 64; ++h) s = fmaf(b3[h], Wg1[h * 32 + i], s);
        F[FB3G + i] = s;
    }
    for (int i = t; i < 32; i += 256) F[FBG1 + i] = bg1[i];
    for (int i = t; i < 128; i += 256) F[FWG2 + i] = Wg2[i];
    for (int i = t; i < 4; i += 256) F[FBG2 + i] = bg2[i];
    if (t == 0) {
        unsigned int m = *mask_in;
        float A[4][4];
        for (int i = 0; i < 4; ++i)
            for (int j = 0; j < 4; ++j) A[i][j] = (i == j) ? 1.f : 0.f;
        int bit = 0;
        for (int i = 0; i < 4; ++i)
            for (int j = i + 1; j < 4; ++j) {
                if ((m >> bit) & 1u) { A[i][j] = 1.f; A[j][i] = 1.f; }
                ++bit;
            }
        float dinv[4];
        for (int i = 0; i < 4; ++i)
            dinv[i] = 1.0f / sqrtf(A[i][0] + A[i][1] + A[i][2] + A[i][3]);
        for (int i = 0; i < 4; ++i)
            for (int j = 0; j < 4; ++j) F[FAHAT + i * 4 + j] = dinv[i] * A[i][j] * dinv[j];
    }
}

// ---------------------------------------------------------------------------
// helpers
// ---------------------------------------------------------------------------
__device__ __forceinline__ unsigned pkf16(float a, float b) {
    unsigned short ha = __builtin_bit_cast(unsigned short, (_Float16)a);
    unsigned short hb = __builtin_bit_cast(unsigned short, (_Float16)b);
    return (unsigned)ha | ((unsigned)hb << 16);
}
__device__ __forceinline__ f32x4 MF(f16x8 a, f16x8 b, f32x4 c) {
    return __builtin_amdgcn_mfma_f32_16x16x32_f16(a, b, c, 0, 0, 0);
}
__device__ __forceinline__ f16x8 ldA(const _Float16* p) {
    return *(const f16x8*)p;            // 16B-aligned ds_read_b128
}
template <int M>
__device__ __forceinline__ f16x8 buildB(const unsigned (&pk)[M][4][2], int kt2, int nt,
                                        int src0, int src1, bool hiSel) {
    unsigned q[4];
#pragma unroll
    for (int p = 0; p < 4; ++p) {
        const int sl = (p >> 1) ? src1 : src0;
        unsigned lo = __shfl(pk[kt2][nt][p & 1], sl);
        unsigned hi = __shfl(pk[kt2 + 1][nt][p & 1], sl);
        q[p] = hiSel ? hi : lo;
    }
    u32x4 t; t.x = q[0]; t.y = q[1]; t.z = q[2]; t.w = q[3];
    return __builtin_bit_cast(f16x8, t);
}

// ---------------------------------------------------------------------------
// Kernel 3: fused MLP+GCN, f16 MFMA. 512 thr = 8 waves (4 waves/SIMD at
// 2 blocks/CU — R5's 256-thr config halved occupancy to 2/SIMD and
// serialized compute vs stores). 2 tiles of 64 nodes per wave.
// emb stored via per-wave LDS transpose -> 1KB-contiguous nontemporal stores.
// ---------------------------------------------------------------------------
__global__ __launch_bounds__(512, 4) void mlp_gcn_mfma(
    const float* __restrict__ x, const char* __restrict__ img,
    float* __restrict__ emb_out, float* __restrict__ out_out)
{
    __shared__ u32x4 smem4[SMEM_BYTES / 16];
    char* smem = (char*)smem4;
    const int tx = threadIdx.x;
    {   // stage weight image (flat, coalesced)
        const u32x4* src = (const u32x4*)img;
        u32x4* dst = (u32x4*)smem;
        for (int i = tx; i < IMG_BYTES / 16; i += 512) dst[i] = src[i];
    }
    __syncthreads();

    const _Float16* wh = (const _Float16*)smem;
    const float* wf = (const float*)(smem + OF32);

    const int wid = tx >> 6, lane = tx & 63;
    const int g = lane >> 4, c = lane & 15;
    const bool g0 = (g == 0);
    const bool hiSel = ((g >> 1) & 1) != 0;
    const int src0 = (g & 1) * 32 + c;
    const int src1 = src0 + 16;

    float* tb = (float*)(smem + IMG_BYTES) + wid * 1024;   // 4KB/wave transpose buf

    // tail constants
    const f32x4 arow = *(const f32x4*)(wf + FAHAT + (c & 3) * 4);
    f32x4 bg1v[2];
    bg1v[0] = *(const f32x4*)(wf + FBG1 + g * 4);
    bg1v[1] = *(const f32x4*)(wf + FBG1 + 16 + g * 4);
    const f32x4 bg2v = *(const f32x4*)(wf + FBG2);
    f32x4 wg2v[2][4];
#pragma unroll
    for (int m = 0; m < 2; ++m)
#pragma unroll
        for (int r = 0; r < 4; ++r)
            wg2v[m][r] = *(const f32x4*)(wf + FWG2 + (m * 16 + g * 4 + r) * 4);

    const size_t nbase0 = ((size_t)blockIdx.x * NWAVE + wid) * 128;  // 2 tiles/wave
    f32x4 xv = *(const f32x4*)(x + (nbase0 + lane) * 4);   // prefetch it=0

#pragma unroll 1
    for (int it = 0; it < 2; ++it) {
        const size_t nbase = nbase0 + (size_t)it * 64;
        // prefetch next tile's x
        const size_t pn = (it < 1) ? (nbase + 64) : nbase;
        f32x4 xnext = *(const f32x4*)(x + (pn + lane) * 4);

        // ---- x -> B-frags (bias slot k=4 gets 1.0) ----
        unsigned xpk01 = pkf16(xv.x, xv.y), xpk23 = pkf16(xv.z, xv.w);
        f16x8 xB[4];
#pragma unroll
        for (int nt = 0; nt < 4; ++nt) {
            int src = nt * 16 + c;
            unsigned a0 = __shfl(xpk01, src), a1 = __shfl(xpk23, src);
            u32x4 t;
            t.x = g0 ? a0 : 0u;
            t.y = g0 ? a1 : 0u;
            t.z = g0 ? 0x00003C00u : 0u;    // f16 {1.0, 0}
            t.w = 0u;
            xB[nt] = __builtin_bit_cast(f16x8, t);
        }

        // ---- L1: h1^T = W1E . xB ----
        unsigned pk1[8][4][2];
#pragma unroll
        for (int mt = 0; mt < 8; ++mt) {
            f16x8 a = ldA(wh + OW1E / 2 + (mt * 16 + c) * 40 + g * 8);
            f32x4 tacc[4];
#pragma unroll
            for (int nt = 0; nt < 4; ++nt) {
                f32x4 z = {0.f, 0.f, 0.f, 0.f};
                tacc[nt] = MF(a, xB[nt], z);
            }
#pragma unroll
            for (int nt = 0; nt < 4; ++nt) {
                pk1[mt][nt][0] = pkf16(fmaxf(tacc[nt][0], 0.f), fmaxf(tacc[nt][1], 0.f));
                pk1[mt][nt][1] = pkf16(fmaxf(tacc[nt][2], 0.f), fmaxf(tacc[nt][3], 0.f));
            }
        }

        // ---- L2: h2^T = W2T . h1^T + b2 ----
        f32x4 acc2[4][4];
#pragma unroll
        for (int mt = 0; mt < 4; ++mt) {
            f32x4 bv = *(const f32x4*)(wf + FB2 + mt * 16 + g * 4);
#pragma unroll
            for (int nt = 0; nt < 4; ++nt) acc2[mt][nt] = bv;
        }
#pragma unroll
        for (int kt = 0; kt < 4; ++kt) {
            f16x8 bf[4];
#pragma unroll
            for (int nt = 0; nt < 4; ++nt) bf[nt] = buildB(pk1, 2 * kt, nt, src0, src1, hiSel);
#pragma unroll
            for (int mt = 0; mt < 4; ++mt) {
                f16x8 a = ldA(wh + OW2T / 2 + (mt * 16 + c) * 136 + kt * 32 + g * 8);
#pragma unroll
                for (int nt = 0; nt < 4; ++nt) acc2[mt][nt] = MF(a, bf[nt], acc2[mt][nt]);
            }
        }
        unsigned pk2a[4][4][2];
#pragma unroll
        for (int mt = 0; mt < 4; ++mt)
#pragma unroll
            for (int nt = 0; nt < 4; ++nt) {
                pk2a[mt][nt][0] = pkf16(fmaxf(acc2[mt][nt][0], 0.f), fmaxf(acc2[mt][nt][1], 0.f));
                pk2a[mt][nt][1] = pkf16(fmaxf(acc2[mt][nt][2], 0.f), fmaxf(acc2[mt][nt][3], 0.f));
            }

        // ---- L3: emb^T = W3T . h2^T + b3 ; tt^T = W3GT . h2^T + b3g ----
        f32x4 acc3[4][4], acc4[2][4];
#pragma unroll
        for (int mt = 0; mt < 4; ++mt) {
            f32x4 bv = *(const f32x4*)(wf + FB3 + mt * 16 + g * 4);
#pragma unroll
            for (int nt = 0; nt < 4; ++nt) acc3[mt][nt] = bv;
        }
#pragma unroll
        for (int mt = 0; mt < 2; ++mt) {
            f32x4 bv = *(const f32x4*)(wf + FB3G + mt * 16 + g * 4);
#pragma unroll
            for (int nt = 0; nt < 4; ++nt) acc4[mt][nt] = bv;
        }
#pragma unroll
        for (int kt = 0; kt < 2; ++kt) {
            f16x8 bf[4];
#pragma unroll
            for (int nt = 0; nt < 4; ++nt) bf[nt] = buildB(pk2a, 2 * kt, nt, src0, src1, hiSel);
#pragma unroll
            for (int mt = 0; mt < 4; ++mt) {
                f16x8 a = ldA(wh + OW3T / 2 + (mt * 16 + c) * 72 + kt * 32 + g * 8);
#pragma unroll
                for (int nt = 0; nt < 4; ++nt) acc3[mt][nt] = MF(a, bf[nt], acc3[mt][nt]);
            }
#pragma unroll
            for (int mt = 0; mt < 2; ++mt) {
                f16x8 a = ldA(wh + OW3GT / 2 + (mt * 16 + c) * 72 + kt * 32 + g * 8);
#pragma unroll
                for (int nt = 0; nt < 4; ++nt) acc4[mt][nt] = MF(a, bf[nt], acc4[mt][nt]);
            }
        }

        // ---- emb store via per-wave LDS transpose ----
#pragma unroll
        for (int nt = 0; nt < 4; ++nt) {
#pragma unroll
            for (int mt = 0; mt < 4; ++mt) {
                int sl = (mt * 4 + g) ^ (c & 7);
                *(f32x4*)(tb + c * 64 + sl * 4) = acc3[mt][nt];
            }
            float* gp = emb_out + (nbase + nt * 16) * 64;
#pragma unroll
            for (int s = 0; s < 4; ++s) {
                int row = s * 4 + g;
                int sl = c ^ (row & 7);
                f32x4 q = *(const f32x4*)(tb + row * 64 + sl * 4);
                __builtin_nontemporal_store(q, (f32x4*)(gp + s * 256 + lane * 4));
            }
        }

        // ---- GCN tail (all qb/DPP calls unconditional, full exec) ----
#pragma unroll
        for (int nt = 0; nt < 4; ++nt) {
            float u[4] = {0.f, 0.f, 0.f, 0.f};
#pragma unroll
            for (int m = 0; m < 2; ++m)
#pragma unroll
                for (int r = 0; r < 4; ++r) {
                    float v = acc4[m][nt][r];
                    float s = bg1v[m][r];
                    s = fmaf(arow.x, qb<0>(v), s);
                    s = fmaf(arow.y, qb<1>(v), s);
                    s = fmaf(arow.z, qb<2>(v), s);
                    s = fmaf(arow.w, qb<3>(v), s);
                    s = fmaxf(s, 0.f);
                    u[0] = fmaf(s, wg2v[m][r].x, u[0]);
                    u[1] = fmaf(s, wg2v[m][r].y, u[1]);
                    u[2] = fmaf(s, wg2v[m][r].z, u[2]);
                    u[3] = fmaf(s, wg2v[m][r].w, u[3]);
                }
#pragma unroll
            for (int o = 0; o < 4; ++o) {
                u[o] += __shfl_xor(u[o], 16);
                u[o] += __shfl_xor(u[o], 32);
            }
            float ov[4];
#pragma unroll
            for (int o = 0; o < 4; ++o) {
                float s = bg2v[o];
                s = fmaf(arow.x, qb<0>(u[o]), s);
                s = fmaf(arow.y, qb<1>(u[o]), s);
                s = fmaf(arow.z, qb<2>(u[o]), s);
                s = fmaf(arow.w, qb<3>(u[o]), s);
                ov[o] = s;
            }
            if (g0) {
                f32x4 t; t.x = ov[0]; t.y = ov[1]; t.z = ov[2]; t.w = ov[3];
                __builtin_nontemporal_store(t, (f32x4*)(out_out + (nbase + nt * 16 + c) * 4));
            }
        }

        xv = xnext;
    }
}

// ---------------------------------------------------------------------------
extern "C" void kernel_launch(void* const* d_in, const int* in_sizes, int n_in,
                              void* d_out, int out_size, void* d_ws, size_t ws_size,
                              hipStream_t stream) {
    const float* x   = (const float*)d_in[0];
    const float* W1  = (const float*)d_in[1];
    const float* b1  = (const float*)d_in[2];
    const float* W2  = (const float*)d_in[3];
    const float* b2  = (const float*)d_in[4];
    const float* W3  = (const float*)d_in[5];
    const float* b3  = (const float*)d_in[6];
    const float* Wg1 = (const float*)d_in[7];
    const float* bg1 = (const float*)d_in[8];
    const float* Wg2 = (const float*)d_in[9];
    const float* bg2 = (const float*)d_in[10];

    unsigned int* mask = (unsigned int*)d_ws;
    char* img = (char*)d_ws + 256;

    float* emb_out = (float*)d_out;
    float* out_out = emb_out + EMB_ELEMS;

    hipMemsetAsync(d_ws, 0, 4, stream);
    adj_kernel<<<NNODE / 256, 256, 0, stream>>>(x, mask);
    prep_kernel<<<1, 256, 0, stream>>>(W1, b1, W2, b2, W3, b3, Wg1, bg1, Wg2, bg2,
                                       mask, img);
    mlp_gcn_mfma<<<NNODE / 1024, 512, 0, stream>>>(x, img, emb_out, out_out);
}

// Round 7
// 184.207 us; speedup vs baseline: 1.5350x; 1.5350x over previous
//
#include <hip/hip_runtime.h>

#define NB 262144
#define NNODE (NB * 4)
#define EMB_ELEMS ((size_t)NNODE * 64)

typedef __attribute__((ext_vector_type(8))) _Float16 f16x8;
typedef __attribute__((ext_vector_type(4))) float f32x4;
typedef __attribute__((ext_vector_type(4))) unsigned int u32x4;

// ---- weight-image layout (bytes), strides padded to 16B multiples ----
#define OW1E  0        // [128][40] f16 : W1^T ext (k0..3=W1, k4=b1, pad 0)
#define OW2T  10240    // [64][136] f16 : W2^T  (row jo, col ji)
#define OW3T  27648    // [64][72]  f16 : W3^T  (row h,  col j)
#define OW3GT 36864    // [32][72]  f16 : (W3@Wg1)^T (row e, col j)
#define OF32  41472    // f32 section
#define IMG_BYTES 42880
// f32 section offsets (floats)
#define FB2   0
#define FB3   64
#define FB3G  128
#define FBG1  160
#define FWG2  192      // [32][4]
#define FBG2  320
#define FAHAT 324      // [4][4]

#define NWAVE 8                                 // 512 threads
#define TRN_BYTES (NWAVE * 4096)                // per-wave 4KB transpose buffers
#define SMEM_BYTES (IMG_BYTES + TRN_BYTES)      // 75648 B -> 2 blocks/CU, 4 waves/SIMD

template <int J>
__device__ __forceinline__ float qb(float v) {      // broadcast quad-lane J (DPP)
    constexpr int ctrl = J | (J << 2) | (J << 4) | (J << 6);
    int r = __builtin_amdgcn_update_dpp(0, __builtin_bit_cast(int, v), ctrl, 0xF, 0xF, true);
    return __builtin_bit_cast(float, r);
}

// ---------------------------------------------------------------------------
// Kernel 1: adjacency union. One thread per NODE (coalesced float4 loads);
// quad lanes = one sample's 4 nodes; dots via DPP quad broadcasts.
// All DPP broadcasts at FULL exec before any divergent branch (R4 bug).
// ---------------------------------------------------------------------------
__global__ __launch_bounds__(256) void adj_kernel(const float* __restrict__ x,
                                                  unsigned int* __restrict__ mask_out) {
    __shared__ unsigned int smask;
    if (threadIdx.x == 0) smask = 0u;
    __syncthreads();

    const int t = blockIdx.x * 256 + threadIdx.x;   // node id (grid exact)
    const int c = t & 3;
    f32x4 v = *(const f32x4*)(x + (size_t)t * 4);
    float nn = sqrtf(v.x * v.x + v.y * v.y + v.z * v.z + v.w * v.w);
    float inv = 1.0f / fmaxf(nn, 1e-8f);

    unsigned int m = 0u;
#define DOTJ(J) do {                                                            \
        const float bx = qb<J>(v.x), by = qb<J>(v.y);                           \
        const float bz = qb<J>(v.z), bw = qb<J>(v.w);                           \
        const float bi = qb<J>(inv);     /* unconditional: full exec mask */    \
        const float d = v.x * bx + v.y * by + v.z * bz + v.w * bw;              \
        if ((int)((J) != c) & (int)(d * inv * bi > 0.5f)) {                     \
            const int i_ = c < (J) ? c : (J);                                   \
            const int j_ = c < (J) ? (J) : c;                                   \
            m |= 1u << (2 * i_ + j_ - 1 - (i_ >> 1));                           \
        }                                                                       \
    } while (0)
    DOTJ(0); DOTJ(1); DOTJ(2); DOTJ(3);
#undef DOTJ

    if (m) atomicOr(&smask, m);
    __syncthreads();
    if (threadIdx.x == 0 && smask) atomicOr(mask_out, smask);
}

// ---------------------------------------------------------------------------
// Kernel 2: build f16 weight image + f32 biases/Ahat in workspace.
// ---------------------------------------------------------------------------
__global__ __launch_bounds__(256) void prep_kernel(
    const float* __restrict__ W1, const float* __restrict__ b1,
    const float* __restrict__ W2, const float* __restrict__ b2,
    const float* __restrict__ W3, const float* __restrict__ b3,
    const float* __restrict__ Wg1, const float* __restrict__ bg1,
    const float* __restrict__ Wg2, const float* __restrict__ bg2,
    const unsigned int* __restrict__ mask_in, char* __restrict__ img)
{
    const int t = threadIdx.x;
    _Float16* H = (_Float16*)img;
    float* F = (float*)(img + OF32);

    for (int i = t; i < 128 * 40; i += 256) {           // W1E
        int j = i / 40, kk = i % 40;
        float v = (kk < 4) ? W1[kk * 128 + j] : (kk == 4 ? b1[j] : 0.f);
        H[OW1E / 2 + i] = (_Float16)v;
    }
    for (int i = t; i < 64 * 136; i += 256) {           // W2T
        int jo = i / 136, ji = i % 136;
        H[OW2T / 2 + i] = (_Float16)(ji < 128 ? W2[ji * 64 + jo] : 0.f);
    }
    for (int i = t; i < 64 * 72; i += 256) {            // W3T
        int h = i / 72, j = i % 72;
        H[OW3T / 2 + i] = (_Float16)(j < 64 ? W3[j * 64 + h] : 0.f);
    }
    for (int i = t; i < 32 * 72; i += 256) {            // W3GT = (W3@Wg1)^T
        int e = i / 72, j = i % 72;
        float s = 0.f;
        if (j < 64)
            for (int h = 0; h < 64; ++h) s = fmaf(W3[j * 64 + h], Wg1[h * 32 + e], s);
        H[OW3GT / 2 + i] = (_Float16)s;
    }
    for (int i = t; i < 64; i += 256) F[FB2 + i] = b2[i];
    for (int i = t; i < 64; i += 256) F[FB3 + i] = b3[i];
    for (int i = t; i < 32; i += 256) {                 // b3g = b3 @ Wg1
        float s = 0.f;
        for (int h = 0; h < 64; ++h) s = fmaf(b3[h], Wg1[h * 32 + i], s);
        F[FB3G + i] = s;
    }
    for (int i = t; i < 32; i += 256) F[FBG1 + i] = bg1[i];
    for (int i = t; i < 128; i += 256) F[FWG2 + i] = Wg2[i];
    for (int i = t; i < 4; i += 256) F[FBG2 + i] = bg2[i];
    if (t == 0) {
        unsigned int m = *mask_in;
        float A[4][4];
        for (int i = 0; i < 4; ++i)
            for (int j = 0; j < 4; ++j) A[i][j] = (i == j) ? 1.f : 0.f;
        int bit = 0;
        for (int i = 0; i < 4; ++i)
            for (int j = i + 1; j < 4; ++j) {
                if ((m >> bit) & 1u) { A[i][j] = 1.f; A[j][i] = 1.f; }
                ++bit;
            }
        float dinv[4];
        for (int i = 0; i < 4; ++i)
            dinv[i] = 1.0f / sqrtf(A[i][0] + A[i][1] + A[i][2] + A[i][3]);
        for (int i = 0; i < 4; ++i)
            for (int j = 0; j < 4; ++j) F[FAHAT + i * 4 + j] = dinv[i] * A[i][j] * dinv[j];
    }
}

// ---------------------------------------------------------------------------
// helpers
// ---------------------------------------------------------------------------
__device__ __forceinline__ unsigned pkf16(float a, float b) {
    unsigned short ha = __builtin_bit_cast(unsigned short, (_Float16)a);
    unsigned short hb = __builtin_bit_cast(unsigned short, (_Float16)b);
    return (unsigned)ha | ((unsigned)hb << 16);
}
__device__ __forceinline__ f32x4 MF(f16x8 a, f16x8 b, f32x4 c) {
    return __builtin_amdgcn_mfma_f32_16x16x32_f16(a, b, c, 0, 0, 0);
}
__device__ __forceinline__ f16x8 ldA(const _Float16* p) {
    return *(const f16x8*)p;            // 16B-aligned ds_read_b128
}
template <int M>
__device__ __forceinline__ f16x8 buildB(const unsigned (&pk)[M][4][2], int kt2, int nt,
                                        int src0, int src1, bool hiSel) {
    unsigned q[4];
#pragma unroll
    for (int p = 0; p < 4; ++p) {
        const int sl = (p >> 1) ? src1 : src0;
        unsigned lo = __shfl(pk[kt2][nt][p & 1], sl);
        unsigned hi = __shfl(pk[kt2 + 1][nt][p & 1], sl);
        q[p] = hiSel ? hi : lo;
    }
    u32x4 t; t.x = q[0]; t.y = q[1]; t.z = q[2]; t.w = q[3];
    return __builtin_bit_cast(f16x8, t);
}

// ---------------------------------------------------------------------------
// Kernel 3: fused MLP+GCN, f16 MFMA. 512 thr = 8 waves, 2 tiles/wave.
// __launch_bounds__(512, 2): R6's (512,4) forced VGPR=64 -> massive scratch
// spill (FETCH +250MB, WRITE +375MB, 195us). (512,2) gives VGPR=128 (R3-
// verified), no spill; LDS 75.6KB -> 2 blocks/CU = 4 waves/SIMD.
// emb stored via per-wave LDS transpose -> 1KB-contiguous nontemporal stores.
// ---------------------------------------------------------------------------
__global__ __launch_bounds__(512, 2) void mlp_gcn_mfma(
    const float* __restrict__ x, const char* __restrict__ img,
    float* __restrict__ emb_out, float* __restrict__ out_out)
{
    __shared__ u32x4 smem4[SMEM_BYTES / 16];
    char* smem = (char*)smem4;
    const int tx = threadIdx.x;
    {   // stage weight image (flat, coalesced)
        const u32x4* src = (const u32x4*)img;
        u32x4* dst = (u32x4*)smem;
        for (int i = tx; i < IMG_BYTES / 16; i += 512) dst[i] = src[i];
    }
    __syncthreads();

    const _Float16* wh = (const _Float16*)smem;
    const float* wf = (const float*)(smem + OF32);

    const int wid = tx >> 6, lane = tx & 63;
    const int g = lane >> 4, c = lane & 15;
    const bool g0 = (g == 0);
    const bool hiSel = ((g >> 1) & 1) != 0;
    const int src0 = (g & 1) * 32 + c;
    const int src1 = src0 + 16;

    float* tb = (float*)(smem + IMG_BYTES) + wid * 1024;   // 4KB/wave transpose buf

    // tail constants
    const f32x4 arow = *(const f32x4*)(wf + FAHAT + (c & 3) * 4);
    f32x4 bg1v[2];
    bg1v[0] = *(const f32x4*)(wf + FBG1 + g * 4);
    bg1v[1] = *(const f32x4*)(wf + FBG1 + 16 + g * 4);
    const f32x4 bg2v = *(const f32x4*)(wf + FBG2);
    f32x4 wg2v[2][4];
#pragma unroll
    for (int m = 0; m < 2; ++m)
#pragma unroll
        for (int r = 0; r < 4; ++r)
            wg2v[m][r] = *(const f32x4*)(wf + FWG2 + (m * 16 + g * 4 + r) * 4);

    const size_t nbase0 = ((size_t)blockIdx.x * NWAVE + wid) * 128;  // 2 tiles/wave
    f32x4 xv = *(const f32x4*)(x + (nbase0 + lane) * 4);   // prefetch it=0

#pragma unroll 1
    for (int it = 0; it < 2; ++it) {
        const size_t nbase = nbase0 + (size_t)it * 64;
        // prefetch next tile's x
        const size_t pn = (it < 1) ? (nbase + 64) : nbase;
        f32x4 xnext = *(const f32x4*)(x + (pn + lane) * 4);

        // ---- x -> B-frags (bias slot k=4 gets 1.0) ----
        unsigned xpk01 = pkf16(xv.x, xv.y), xpk23 = pkf16(xv.z, xv.w);
        f16x8 xB[4];
#pragma unroll
        for (int nt = 0; nt < 4; ++nt) {
            int src = nt * 16 + c;
            unsigned a0 = __shfl(xpk01, src), a1 = __shfl(xpk23, src);
            u32x4 t;
            t.x = g0 ? a0 : 0u;
            t.y = g0 ? a1 : 0u;
            t.z = g0 ? 0x00003C00u : 0u;    // f16 {1.0, 0}
            t.w = 0u;
            xB[nt] = __builtin_bit_cast(f16x8, t);
        }

        // ---- L1: h1^T = W1E . xB ----
        unsigned pk1[8][4][2];
#pragma unroll
        for (int mt = 0; mt < 8; ++mt) {
            f16x8 a = ldA(wh + OW1E / 2 + (mt * 16 + c) * 40 + g * 8);
            f32x4 tacc[4];
#pragma unroll
            for (int nt = 0; nt < 4; ++nt) {
                f32x4 z = {0.f, 0.f, 0.f, 0.f};
                tacc[nt] = MF(a, xB[nt], z);
            }
#pragma unroll
            for (int nt = 0; nt < 4; ++nt) {
                pk1[mt][nt][0] = pkf16(fmaxf(tacc[nt][0], 0.f), fmaxf(tacc[nt][1], 0.f));
                pk1[mt][nt][1] = pkf16(fmaxf(tacc[nt][2], 0.f), fmaxf(tacc[nt][3], 0.f));
            }
        }

        // ---- L2: h2^T = W2T . h1^T + b2 ----
        f32x4 acc2[4][4];
#pragma unroll
        for (int mt = 0; mt < 4; ++mt) {
            f32x4 bv = *(const f32x4*)(wf + FB2 + mt * 16 + g * 4);
#pragma unroll
            for (int nt = 0; nt < 4; ++nt) acc2[mt][nt] = bv;
        }
#pragma unroll
        for (int kt = 0; kt < 4; ++kt) {
            f16x8 bf[4];
#pragma unroll
            for (int nt = 0; nt < 4; ++nt) bf[nt] = buildB(pk1, 2 * kt, nt, src0, src1, hiSel);
#pragma unroll
            for (int mt = 0; mt < 4; ++mt) {
                f16x8 a = ldA(wh + OW2T / 2 + (mt * 16 + c) * 136 + kt * 32 + g * 8);
#pragma unroll
                for (int nt = 0; nt < 4; ++nt) acc2[mt][nt] = MF(a, bf[nt], acc2[mt][nt]);
            }
        }
        unsigned pk2a[4][4][2];
#pragma unroll
        for (int mt = 0; mt < 4; ++mt)
#pragma unroll
            for (int nt = 0; nt < 4; ++nt) {
                pk2a[mt][nt][0] = pkf16(fmaxf(acc2[mt][nt][0], 0.f), fmaxf(acc2[mt][nt][1], 0.f));
                pk2a[mt][nt][1] = pkf16(fmaxf(acc2[mt][nt][2], 0.f), fmaxf(acc2[mt][nt][3], 0.f));
            }

        // ---- L3: emb^T = W3T . h2^T + b3 ; tt^T = W3GT . h2^T + b3g ----
        f32x4 acc3[4][4], acc4[2][4];
#pragma unroll
        for (int mt = 0; mt < 4; ++mt) {
            f32x4 bv = *(const f32x4*)(wf + FB3 + mt * 16 + g * 4);
#pragma unroll
            for (int nt = 0; nt < 4; ++nt) acc3[mt][nt] = bv;
        }
#pragma unroll
        for (int mt = 0; mt < 2; ++mt) {
            f32x4 bv = *(const f32x4*)(wf + FB3G + mt * 16 + g * 4);
#pragma unroll
            for (int nt = 0; nt < 4; ++nt) acc4[mt][nt] = bv;
        }
#pragma unroll
        for (int kt = 0; kt < 2; ++kt) {
            f16x8 bf[4];
#pragma unroll
            for (int nt = 0; nt < 4; ++nt) bf[nt] = buildB(pk2a, 2 * kt, nt, src0, src1, hiSel);
#pragma unroll
            for (int mt = 0; mt < 4; ++mt) {
                f16x8 a = ldA(wh + OW3T / 2 + (mt * 16 + c) * 72 + kt * 32 + g * 8);
#pragma unroll
                for (int nt = 0; nt < 4; ++nt) acc3[mt][nt] = MF(a, bf[nt], acc3[mt][nt]);
            }
#pragma unroll
            for (int mt = 0; mt < 2; ++mt) {
                f16x8 a = ldA(wh + OW3GT / 2 + (mt * 16 + c) * 72 + kt * 32 + g * 8);
#pragma unroll
                for (int nt = 0; nt < 4; ++nt) acc4[mt][nt] = MF(a, bf[nt], acc4[mt][nt]);
            }
        }

        // ---- emb store via per-wave LDS transpose ----
#pragma unroll
        for (int nt = 0; nt < 4; ++nt) {
#pragma unroll
            for (int mt = 0; mt < 4; ++mt) {
                int sl = (mt * 4 + g) ^ (c & 7);
                *(f32x4*)(tb + c * 64 + sl * 4) = acc3[mt][nt];
            }
            float* gp = emb_out + (nbase + nt * 16) * 64;
#pragma unroll
            for (int s = 0; s < 4; ++s) {
                int row = s * 4 + g;
                int sl = c ^ (row & 7);
                f32x4 q = *(const f32x4*)(tb + row * 64 + sl * 4);
                __builtin_nontemporal_store(q, (f32x4*)(gp + s * 256 + lane * 4));
            }
        }

        // ---- GCN tail (all qb/DPP calls unconditional, full exec) ----
#pragma unroll
        for (int nt = 0; nt < 4; ++nt) {
            float u[4] = {0.f, 0.f, 0.f, 0.f};
#pragma unroll
            for (int m = 0; m < 2; ++m)
#pragma unroll
                for (int r = 0; r < 4; ++r) {
                    float v = acc4[m][nt][r];
                    float s = bg1v[m][r];
                    s = fmaf(arow.x, qb<0>(v), s);
                    s = fmaf(arow.y, qb<1>(v), s);
                    s = fmaf(arow.z, qb<2>(v), s);
                    s = fmaf(arow.w, qb<3>(v), s);
                    s = fmaxf(s, 0.f);
                    u[0] = fmaf(s, wg2v[m][r].x, u[0]);
                    u[1] = fmaf(s, wg2v[m][r].y, u[1]);
                    u[2] = fmaf(s, wg2v[m][r].z, u[2]);
                    u[3] = fmaf(s, wg2v[m][r].w, u[3]);
                }
#pragma unroll
            for (int o = 0; o < 4; ++o) {
                u[o] += __shfl_xor(u[o], 16);
                u[o] += __shfl_xor(u[o], 32);
            }
            float ov[4];
#pragma unroll
            for (int o = 0; o < 4; ++o) {
                float s = bg2v[o];
                s = fmaf(arow.x, qb<0>(u[o]), s);
                s = fmaf(arow.y, qb<1>(u[o]), s);
                s = fmaf(arow.z, qb<2>(u[o]), s);
                s = fmaf(arow.w, qb<3>(u[o]), s);
                ov[o] = s;
            }
            if (g0) {
                f32x4 t; t.x = ov[0]; t.y = ov[1]; t.z = ov[2]; t.w = ov[3];
                __builtin_nontemporal_store(t, (f32x4*)(out_out + (nbase + nt * 16 + c) * 4));
            }
        }

        xv = xnext;
    }
}

// ---------------------------------------------------------------------------
extern "C" void kernel_launch(void* const* d_in, const int* in_sizes, int n_in,
                              void* d_out, int out_size, void* d_ws, size_t ws_size,
                              hipStream_t stream) {
    const float* x   = (const float*)d_in[0];
    const float* W1  = (const float*)d_in[1];
    const float* b1  = (const float*)d_in[2];
    const float* W2  = (const float*)d_in[3];
    const float* b2  = (const float*)d_in[4];
    const float* W3  = (const float*)d_in[5];
    const float* b3  = (const float*)d_in[6];
    const float* Wg1 = (const float*)d_in[7];
    const float* bg1 = (const float*)d_in[8];
    const float* Wg2 = (const float*)d_in[9];
    const float* bg2 = (const float*)d_in[10];

    unsigned int* mask = (unsigned int*)d_ws;
    char* img = (char*)d_ws + 256;

    float* emb_out = (float*)d_out;
    float* out_out = emb_out + EMB_ELEMS;

    hipMemsetAsync(d_ws, 0, 4, stream);
    adj_kernel<<<NNODE / 256, 256, 0, stream>>>(x, mask);
    prep_kernel<<<1, 256, 0, stream>>>(W1, b1, W2, b2, W3, b3, Wg1, bg1, Wg2, bg2,
                                       mask, img);
    mlp_gcn_mfma<<<NNODE / 1024, 512, 0, stream>>>(x, img, emb_out, out_out);
}

// Round 8
// 133.217 us; speedup vs baseline: 2.1226x; 1.3828x over previous
//
#include <hip/hip_runtime.h>

#define NB 262144
#define NNODE (NB * 4)
#define EMB_ELEMS ((size_t)NNODE * 64)
#define ADJ_BLOCKS (NNODE / 256)               // 4096

typedef __attribute__((ext_vector_type(8))) _Float16 f16x8;
typedef __attribute__((ext_vector_type(4))) float f32x4;
typedef __attribute__((ext_vector_type(4))) unsigned int u32x4;

// ---- weight-image layout (bytes), strides padded to 16B multiples ----
#define OW1E  0        // [128][40] f16 : W1^T ext (k0..3=W1, k4=b1, pad 0)
#define OW2T  10240    // [64][136] f16 : W2^T  (row jo, col ji)
#define OW3T  27648    // [64][72]  f16 : W3^T  (row h,  col j)
#define OW3GT 36864    // [32][72]  f16 : (W3@Wg1)^T (row e, col j)
#define OF32  41472    // f32 section
#define IMG_BYTES 42880
// f32 section offsets (floats)
#define FB2   0
#define FB3   64
#define FB3G  128
#define FBG1  160
#define FWG2  192      // [32][4]
#define FBG2  320
#define FAHAT 324      // [4][4]

#define NWAVE 8                                 // 512 threads
#define TRN_BYTES (NWAVE * 4096)                // per-wave 4KB transpose buffers
#define SMEM_BYTES (IMG_BYTES + TRN_BYTES)      // 75648 B -> 2 blocks/CU, 4 waves/SIMD

template <int J>
__device__ __forceinline__ float qb(float v) {      // broadcast quad-lane J (DPP)
    constexpr int ctrl = J | (J << 2) | (J << 4) | (J << 6);
    int r = __builtin_amdgcn_update_dpp(0, __builtin_bit_cast(int, v), ctrl, 0xF, 0xF, true);
    return __builtin_bit_cast(float, r);
}

// ---------------------------------------------------------------------------
// Kernel 1: adjacency union. One thread per NODE (coalesced float4 loads);
// quad lanes = one sample's 4 nodes; dots via DPP quad broadcasts (all at
// FULL exec before any divergent branch — R4 bug).
// R7 fix: NO global atomics. Each block writes its 6-bit mask to its own
// slot (plain store); prep_kernel block 0 OR-reduces the 4096 words.
// (R1-R7 funneled 4096 atomicOr through ONE address -> ~40-50us serialized.)
// ---------------------------------------------------------------------------
__global__ __launch_bounds__(256) void adj_kernel(const float* __restrict__ x,
                                                  unsigned int* __restrict__ mask_arr) {
    __shared__ unsigned int smask;
    if (threadIdx.x == 0) smask = 0u;
    __syncthreads();

    const int t = blockIdx.x * 256 + threadIdx.x;   // node id (grid exact)
    const int c = t & 3;
    f32x4 v = *(const f32x4*)(x + (size_t)t * 4);
    float nn = sqrtf(v.x * v.x + v.y * v.y + v.z * v.z + v.w * v.w);
    float inv = 1.0f / fmaxf(nn, 1e-8f);

    unsigned int m = 0u;
#define DOTJ(J) do {                                                            \
        const float bx = qb<J>(v.x), by = qb<J>(v.y);                           \
        const float bz = qb<J>(v.z), bw = qb<J>(v.w);                           \
        const float bi = qb<J>(inv);     /* unconditional: full exec mask */    \
        const float d = v.x * bx + v.y * by + v.z * bz + v.w * bw;              \
        if ((int)((J) != c) & (int)(d * inv * bi > 0.5f)) {                     \
            const int i_ = c < (J) ? c : (J);                                   \
            const int j_ = c < (J) ? (J) : c;                                   \
            m |= 1u << (2 * i_ + j_ - 1 - (i_ >> 1));                           \
        }                                                                       \
    } while (0)
    DOTJ(0); DOTJ(1); DOTJ(2); DOTJ(3);
#undef DOTJ

    if (m) atomicOr(&smask, m);
    __syncthreads();
    if (threadIdx.x == 0) mask_arr[blockIdx.x] = smask;   // unconditional: no stale ws
}

// ---------------------------------------------------------------------------
// Kernel 2: build f16 weight image + f32 biases/Ahat. 4 blocks, one section
// each (R7: was 1 block ~8us serial).
// ---------------------------------------------------------------------------
__global__ __launch_bounds__(256) void prep_kernel(
    const float* __restrict__ W1, const float* __restrict__ b1,
    const float* __restrict__ W2, const float* __restrict__ b2,
    const float* __restrict__ W3, const float* __restrict__ b3,
    const float* __restrict__ Wg1, const float* __restrict__ bg1,
    const float* __restrict__ Wg2, const float* __restrict__ bg2,
    const unsigned int* __restrict__ mask_arr, char* __restrict__ img)
{
    const int t = threadIdx.x;
    const int bid = blockIdx.x;
    _Float16* H = (_Float16*)img;
    float* F = (float*)(img + OF32);

    if (bid == 0) {
        // ---- OR-reduce the 4096 per-block masks ----
        __shared__ unsigned red[256];
        unsigned um = 0u;
        for (int i = t; i < ADJ_BLOCKS; i += 256) um |= mask_arr[i];
        red[t] = um;
        __syncthreads();
        for (int s = 128; s > 0; s >>= 1) {
            if (t < s) red[t] |= red[t + s];
            __syncthreads();
        }
        const unsigned m = red[0];

        // ---- f32 consts ----
        for (int i = t; i < 64; i += 256) F[FB2 + i] = b2[i];
        for (int i = t; i < 64; i += 256) F[FB3 + i] = b3[i];
        for (int i = t; i < 32; i += 256) {                 // b3g = b3 @ Wg1
            float s = 0.f;
            for (int h = 0; h < 64; ++h) s = fmaf(b3[h], Wg1[h * 32 + i], s);
            F[FB3G + i] = s;
        }
        for (int i = t; i < 32; i += 256) F[FBG1 + i] = bg1[i];
        for (int i = t; i < 128; i += 256) F[FWG2 + i] = Wg2[i];
        for (int i = t; i < 4; i += 256) F[FBG2 + i] = bg2[i];
        if (t == 0) {
            float A[4][4];
            for (int i = 0; i < 4; ++i)
                for (int j = 0; j < 4; ++j) A[i][j] = (i == j) ? 1.f : 0.f;
            int bit = 0;
            for (int i = 0; i < 4; ++i)
                for (int j = i + 1; j < 4; ++j) {
                    if ((m >> bit) & 1u) { A[i][j] = 1.f; A[j][i] = 1.f; }
                    ++bit;
                }
            float dinv[4];
            for (int i = 0; i < 4; ++i)
                dinv[i] = 1.0f / sqrtf(A[i][0] + A[i][1] + A[i][2] + A[i][3]);
            for (int i = 0; i < 4; ++i)
                for (int j = 0; j < 4; ++j) F[FAHAT + i * 4 + j] = dinv[i] * A[i][j] * dinv[j];
        }
    } else if (bid == 1) {
        for (int i = t; i < 128 * 40; i += 256) {           // W1E
            int j = i / 40, kk = i % 40;
            float v = (kk < 4) ? W1[kk * 128 + j] : (kk == 4 ? b1[j] : 0.f);
            H[OW1E / 2 + i] = (_Float16)v;
        }
    } else if (bid == 2) {
        for (int i = t; i < 64 * 136; i += 256) {           // W2T
            int jo = i / 136, ji = i % 136;
            H[OW2T / 2 + i] = (_Float16)(ji < 128 ? W2[ji * 64 + jo] : 0.f);
        }
    } else {
        for (int i = t; i < 64 * 72; i += 256) {            // W3T
            int h = i / 72, j = i % 72;
            H[OW3T / 2 + i] = (_Float16)(j < 64 ? W3[j * 64 + h] : 0.f);
        }
        for (int i = t; i < 32 * 72; i += 256) {            // W3GT = (W3@Wg1)^T
            int e = i / 72, j = i % 72;
            float s = 0.f;
            if (j < 64)
                for (int h = 0; h < 64; ++h) s = fmaf(W3[j * 64 + h], Wg1[h * 32 + e], s);
            H[OW3GT / 2 + i] = (_Float16)s;
        }
    }
}

// ---------------------------------------------------------------------------
// helpers
// ---------------------------------------------------------------------------
__device__ __forceinline__ unsigned pkf16(float a, float b) {
    unsigned short ha = __builtin_bit_cast(unsigned short, (_Float16)a);
    unsigned short hb = __builtin_bit_cast(unsigned short, (_Float16)b);
    return (unsigned)ha | ((unsigned)hb << 16);
}
__device__ __forceinline__ f32x4 MF(f16x8 a, f16x8 b, f32x4 c) {
    return __builtin_amdgcn_mfma_f32_16x16x32_f16(a, b, c, 0, 0, 0);
}
__device__ __forceinline__ f16x8 ldA(const _Float16* p) {
    return *(const f16x8*)p;            // 16B-aligned ds_read_b128
}
template <int M>
__device__ __forceinline__ f16x8 buildB(const unsigned (&pk)[M][4][2], int kt2, int nt,
                                        int src0, int src1, bool hiSel) {
    unsigned q[4];
#pragma unroll
    for (int p = 0; p < 4; ++p) {
        const int sl = (p >> 1) ? src1 : src0;
        unsigned lo = __shfl(pk[kt2][nt][p & 1], sl);
        unsigned hi = __shfl(pk[kt2 + 1][nt][p & 1], sl);
        q[p] = hiSel ? hi : lo;
    }
    u32x4 t; t.x = q[0]; t.y = q[1]; t.z = q[2]; t.w = q[3];
    return __builtin_bit_cast(f16x8, t);
}

// ---------------------------------------------------------------------------
// Kernel 3: fused MLP+GCN, f16 MFMA. 512 thr = 8 waves, 2 tiles/wave,
// __launch_bounds__(512,2) (VGPR 128, no spill — R6's (512,4) spilled).
// R7 test: PLAIN stores (were nontemporal). Each wave-store instruction
// covers 1KB contiguous (full 128B lines) so no RFO risk; NT bypasses L2
// write-combining and is suspected of throttling at ~2.8 TB/s.
// ---------------------------------------------------------------------------
__global__ __launch_bounds__(512, 2) void mlp_gcn_mfma(
    const float* __restrict__ x, const char* __restrict__ img,
    float* __restrict__ emb_out, float* __restrict__ out_out)
{
    __shared__ u32x4 smem4[SMEM_BYTES / 16];
    char* smem = (char*)smem4;
    const int tx = threadIdx.x;
    {   // stage weight image (flat, coalesced)
        const u32x4* src = (const u32x4*)img;
        u32x4* dst = (u32x4*)smem;
        for (int i = tx; i < IMG_BYTES / 16; i += 512) dst[i] = src[i];
    }
    __syncthreads();

    const _Float16* wh = (const _Float16*)smem;
    const float* wf = (const float*)(smem + OF32);

    const int wid = tx >> 6, lane = tx & 63;
    const int g = lane >> 4, c = lane & 15;
    const bool g0 = (g == 0);
    const bool hiSel = ((g >> 1) & 1) != 0;
    const int src0 = (g & 1) * 32 + c;
    const int src1 = src0 + 16;

    float* tb = (float*)(smem + IMG_BYTES) + wid * 1024;   // 4KB/wave transpose buf

    // tail constants
    const f32x4 arow = *(const f32x4*)(wf + FAHAT + (c & 3) * 4);
    f32x4 bg1v[2];
    bg1v[0] = *(const f32x4*)(wf + FBG1 + g * 4);
    bg1v[1] = *(const f32x4*)(wf + FBG1 + 16 + g * 4);
    const f32x4 bg2v = *(const f32x4*)(wf + FBG2);
    f32x4 wg2v[2][4];
#pragma unroll
    for (int m = 0; m < 2; ++m)
#pragma unroll
        for (int r = 0; r < 4; ++r)
            wg2v[m][r] = *(const f32x4*)(wf + FWG2 + (m * 16 + g * 4 + r) * 4);

    const size_t nbase0 = ((size_t)blockIdx.x * NWAVE + wid) * 128;  // 2 tiles/wave
    f32x4 xv = *(const f32x4*)(x + (nbase0 + lane) * 4);   // prefetch it=0

#pragma unroll 1
    for (int it = 0; it < 2; ++it) {
        const size_t nbase = nbase0 + (size_t)it * 64;
        // prefetch next tile's x
        const size_t pn = (it < 1) ? (nbase + 64) : nbase;
        f32x4 xnext = *(const f32x4*)(x + (pn + lane) * 4);

        // ---- x -> B-frags (bias slot k=4 gets 1.0) ----
        unsigned xpk01 = pkf16(xv.x, xv.y), xpk23 = pkf16(xv.z, xv.w);
        f16x8 xB[4];
#pragma unroll
        for (int nt = 0; nt < 4; ++nt) {
            int src = nt * 16 + c;
            unsigned a0 = __shfl(xpk01, src), a1 = __shfl(xpk23, src);
            u32x4 t;
            t.x = g0 ? a0 : 0u;
            t.y = g0 ? a1 : 0u;
            t.z = g0 ? 0x00003C00u : 0u;    // f16 {1.0, 0}
            t.w = 0u;
            xB[nt] = __builtin_bit_cast(f16x8, t);
        }

        // ---- L1: h1^T = W1E . xB ----
        unsigned pk1[8][4][2];
#pragma unroll
        for (int mt = 0; mt < 8; ++mt) {
            f16x8 a = ldA(wh + OW1E / 2 + (mt * 16 + c) * 40 + g * 8);
            f32x4 tacc[4];
#pragma unroll
            for (int nt = 0; nt < 4; ++nt) {
                f32x4 z = {0.f, 0.f, 0.f, 0.f};
                tacc[nt] = MF(a, xB[nt], z);
            }
#pragma unroll
            for (int nt = 0; nt < 4; ++nt) {
                pk1[mt][nt][0] = pkf16(fmaxf(tacc[nt][0], 0.f), fmaxf(tacc[nt][1], 0.f));
                pk1[mt][nt][1] = pkf16(fmaxf(tacc[nt][2], 0.f), fmaxf(tacc[nt][3], 0.f));
            }
        }

        // ---- L2: h2^T = W2T . h1^T + b2 ----
        f32x4 acc2[4][4];
#pragma unroll
        for (int mt = 0; mt < 4; ++mt) {
            f32x4 bv = *(const f32x4*)(wf + FB2 + mt * 16 + g * 4);
#pragma unroll
            for (int nt = 0; nt < 4; ++nt) acc2[mt][nt] = bv;
        }
#pragma unroll
        for (int kt = 0; kt < 4; ++kt) {
            f16x8 bf[4];
#pragma unroll
            for (int nt = 0; nt < 4; ++nt) bf[nt] = buildB(pk1, 2 * kt, nt, src0, src1, hiSel);
#pragma unroll
            for (int mt = 0; mt < 4; ++mt) {
                f16x8 a = ldA(wh + OW2T / 2 + (mt * 16 + c) * 136 + kt * 32 + g * 8);
#pragma unroll
                for (int nt = 0; nt < 4; ++nt) acc2[mt][nt] = MF(a, bf[nt], acc2[mt][nt]);
            }
        }
        unsigned pk2a[4][4][2];
#pragma unroll
        for (int mt = 0; mt < 4; ++mt)
#pragma unroll
            for (int nt = 0; nt < 4; ++nt) {
                pk2a[mt][nt][0] = pkf16(fmaxf(acc2[mt][nt][0], 0.f), fmaxf(acc2[mt][nt][1], 0.f));
                pk2a[mt][nt][1] = pkf16(fmaxf(acc2[mt][nt][2], 0.f), fmaxf(acc2[mt][nt][3], 0.f));
            }

        // ---- L3: emb^T = W3T . h2^T + b3 ; tt^T = W3GT . h2^T + b3g ----
        f32x4 acc3[4][4], acc4[2][4];
#pragma unroll
        for (int mt = 0; mt < 4; ++mt) {
            f32x4 bv = *(const f32x4*)(wf + FB3 + mt * 16 + g * 4);
#pragma unroll
            for (int nt = 0; nt < 4; ++nt) acc3[mt][nt] = bv;
        }
#pragma unroll
        for (int mt = 0; mt < 2; ++mt) {
            f32x4 bv = *(const f32x4*)(wf + FB3G + mt * 16 + g * 4);
#pragma unroll
            for (int nt = 0; nt < 4; ++nt) acc4[mt][nt] = bv;
        }
#pragma unroll
        for (int kt = 0; kt < 2; ++kt) {
            f16x8 bf[4];
#pragma unroll
            for (int nt = 0; nt < 4; ++nt) bf[nt] = buildB(pk2a, 2 * kt, nt, src0, src1, hiSel);
#pragma unroll
            for (int mt = 0; mt < 4; ++mt) {
                f16x8 a = ldA(wh + OW3T / 2 + (mt * 16 + c) * 72 + kt * 32 + g * 8);
#pragma unroll
                for (int nt = 0; nt < 4; ++nt) acc3[mt][nt] = MF(a, bf[nt], acc3[mt][nt]);
            }
#pragma unroll
            for (int mt = 0; mt < 2; ++mt) {
                f16x8 a = ldA(wh + OW3GT / 2 + (mt * 16 + c) * 72 + kt * 32 + g * 8);
#pragma unroll
                for (int nt = 0; nt < 4; ++nt) acc4[mt][nt] = MF(a, bf[nt], acc4[mt][nt]);
            }
        }

        // ---- emb store via per-wave LDS transpose (plain stores this round) ----
#pragma unroll
        for (int nt = 0; nt < 4; ++nt) {
#pragma unroll
            for (int mt = 0; mt < 4; ++mt) {
                int sl = (mt * 4 + g) ^ (c & 7);
                *(f32x4*)(tb + c * 64 + sl * 4) = acc3[mt][nt];
            }
            float* gp = emb_out + (nbase + nt * 16) * 64;
#pragma unroll
            for (int s = 0; s < 4; ++s) {
                int row = s * 4 + g;
                int sl = c ^ (row & 7);
                f32x4 q = *(const f32x4*)(tb + row * 64 + sl * 4);
                *(f32x4*)(gp + s * 256 + lane * 4) = q;
            }
        }

        // ---- GCN tail (all qb/DPP calls unconditional, full exec) ----
#pragma unroll
        for (int nt = 0; nt < 4; ++nt) {
            float u[4] = {0.f, 0.f, 0.f, 0.f};
#pragma unroll
            for (int m = 0; m < 2; ++m)
#pragma unroll
                for (int r = 0; r < 4; ++r) {
                    float v = acc4[m][nt][r];
                    float s = bg1v[m][r];
                    s = fmaf(arow.x, qb<0>(v), s);
                    s = fmaf(arow.y, qb<1>(v), s);
                    s = fmaf(arow.z, qb<2>(v), s);
                    s = fmaf(arow.w, qb<3>(v), s);
                    s = fmaxf(s, 0.f);
                    u[0] = fmaf(s, wg2v[m][r].x, u[0]);
                    u[1] = fmaf(s, wg2v[m][r].y, u[1]);
                    u[2] = fmaf(s, wg2v[m][r].z, u[2]);
                    u[3] = fmaf(s, wg2v[m][r].w, u[3]);
                }
#pragma unroll
            for (int o = 0; o < 4; ++o) {
                u[o] += __shfl_xor(u[o], 16);
                u[o] += __shfl_xor(u[o], 32);
            }
            float ov[4];
#pragma unroll
            for (int o = 0; o < 4; ++o) {
                float s = bg2v[o];
                s = fmaf(arow.x, qb<0>(u[o]), s);
                s = fmaf(arow.y, qb<1>(u[o]), s);
                s = fmaf(arow.z, qb<2>(u[o]), s);
                s = fmaf(arow.w, qb<3>(u[o]), s);
                ov[o] = s;
            }
            if (g0) {
                f32x4 t; t.x = ov[0]; t.y = ov[1]; t.z = ov[2]; t.w = ov[3];
                *(f32x4*)(out_out + (nbase + nt * 16 + c) * 4) = t;
            }
        }

        xv = xnext;
    }
}

// ---------------------------------------------------------------------------
extern "C" void kernel_launch(void* const* d_in, const int* in_sizes, int n_in,
                              void* d_out, int out_size, void* d_ws, size_t ws_size,
                              hipStream_t stream) {
    const float* x   = (const float*)d_in[0];
    const float* W1  = (const float*)d_in[1];
    const float* b1  = (const float*)d_in[2];
    const float* W2  = (const float*)d_in[3];
    const float* b2  = (const float*)d_in[4];
    const float* W3  = (const float*)d_in[5];
    const float* b3  = (const float*)d_in[6];
    const float* Wg1 = (const float*)d_in[7];
    const float* bg1 = (const float*)d_in[8];
    const float* Wg2 = (const float*)d_in[9];
    const float* bg2 = (const float*)d_in[10];

    unsigned int* mask_arr = (unsigned int*)d_ws;          // 4096 words, all rewritten
    char* img = (char*)d_ws + 16640;                       // past mask array, 256-aligned

    float* emb_out = (float*)d_out;
    float* out_out = emb_out + EMB_ELEMS;

    adj_kernel<<<ADJ_BLOCKS, 256, 0, stream>>>(x, mask_arr);
    prep_kernel<<<4, 256, 0, stream>>>(W1, b1, W2, b2, W3, b3, Wg1, bg1, Wg2, bg2,
                                       mask_arr, img);
    mlp_gcn_mfma<<<NNODE / 1024, 512, 0, stream>>>(x, img, emb_out, out_out);
}

// Round 9
// 118.138 us; speedup vs baseline: 2.3935x; 1.1276x over previous
//
#include <hip/hip_runtime.h>

#define NB 262144
#define NNODE (NB * 4)
#define EMB_ELEMS ((size_t)NNODE * 64)
#define ADJ_BLOCKS (NNODE / 256)               // 4096

typedef __attribute__((ext_vector_type(8))) _Float16 f16x8;
typedef __attribute__((ext_vector_type(4))) float f32x4;
typedef __attribute__((ext_vector_type(4))) unsigned int u32x4;

// ---- weight-image layout (bytes), strides padded to 16B multiples ----
#define OW1E  0        // [128][40] f16 : W1^T ext (k0..3=W1, k4=b1, pad 0)
#define OW2T  10240    // [64][136] f16 : W2^T  (row jo, col ji)
#define OW3T  27648    // [64][72]  f16 : W3^T  (row h,  col j)
#define OW3GT 36864    // [32][72]  f16 : (W3@Wg1)^T (row e, col j)
#define OF32  41472    // f32 section
#define IMG_BYTES 42880
// f32 section offsets (floats)
#define FB2   0
#define FB3   64
#define FB3G  128
#define FBG1  160
#define FWG2  192      // [32][4]
#define FBG2  320
#define FAHAT 324      // [4][4]

#define NWAVE 8                                 // 512 threads
// Per-wave scratch: B-staging [64 node][36 f16] = 4608B (also covers the
// 4KB emb-transpose use). Stride 36 -> bank stride 18: c*18 mod 32 hits all
// 16 distinct even banks -> <=2-way conflicts (free, m136).
#define SB_STRIDE 36
#define WBUF_BYTES (64 * SB_STRIDE * 2)         // 4608
#define SMEM_BYTES (IMG_BYTES + NWAVE * WBUF_BYTES)  // 79744 <= 80KB -> 2 blk/CU

template <int J>
__device__ __forceinline__ float qb(float v) {      // broadcast quad-lane J (DPP)
    constexpr int ctrl = J | (J << 2) | (J << 4) | (J << 6);
    int r = __builtin_amdgcn_update_dpp(0, __builtin_bit_cast(int, v), ctrl, 0xF, 0xF, true);
    return __builtin_bit_cast(float, r);
}

// xor-16 / xor-32 lane sums via gfx950 permlane swaps (VALU pipe, not LDS).
// With a=b=u, after swap a+b = pairwise group sum in ALL lanes (direction-
// agnostic: either swap convention yields the same sum).
__device__ __forceinline__ float sum_xor16(float u) {
    float a = u, b = u;
    asm("v_permlane16_swap_b32 %0, %1" : "+v"(a), "+v"(b));
    return a + b;
}
__device__ __forceinline__ float sum_xor32(float u) {
    float a = u, b = u;
    asm("v_permlane32_swap_b32 %0, %1" : "+v"(a), "+v"(b));
    return a + b;
}

// ---------------------------------------------------------------------------
// Kernel 1: adjacency union. One thread per NODE; quad lanes = one sample.
// DPP broadcasts at FULL exec (R4 bug). Per-block mask -> own slot (R8: no
// global atomics); prep block 0 OR-reduces.
// ---------------------------------------------------------------------------
__global__ __launch_bounds__(256) void adj_kernel(const float* __restrict__ x,
                                                  unsigned int* __restrict__ mask_arr) {
    __shared__ unsigned int smask;
    if (threadIdx.x == 0) smask = 0u;
    __syncthreads();

    const int t = blockIdx.x * 256 + threadIdx.x;
    const int c = t & 3;
    f32x4 v = *(const f32x4*)(x + (size_t)t * 4);
    float nn = sqrtf(v.x * v.x + v.y * v.y + v.z * v.z + v.w * v.w);
    float inv = 1.0f / fmaxf(nn, 1e-8f);

    unsigned int m = 0u;
#define DOTJ(J) do {                                                            \
        const float bx = qb<J>(v.x), by = qb<J>(v.y);                           \
        const float bz = qb<J>(v.z), bw = qb<J>(v.w);                           \
        const float bi = qb<J>(inv);                                            \
        const float d = v.x * bx + v.y * by + v.z * bz + v.w * bw;              \
        if ((int)((J) != c) & (int)(d * inv * bi > 0.5f)) {                     \
            const int i_ = c < (J) ? c : (J);                                   \
            const int j_ = c < (J) ? (J) : c;                                   \
            m |= 1u << (2 * i_ + j_ - 1 - (i_ >> 1));                           \
        }                                                                       \
    } while (0)
    DOTJ(0); DOTJ(1); DOTJ(2); DOTJ(3);
#undef DOTJ

    if (m) atomicOr(&smask, m);
    __syncthreads();
    if (threadIdx.x == 0) mask_arr[blockIdx.x] = smask;
}

// ---------------------------------------------------------------------------
// Kernel 2: build f16 weight image + f32 biases/Ahat. 4 parallel blocks.
// ---------------------------------------------------------------------------
__global__ __launch_bounds__(256) void prep_kernel(
    const float* __restrict__ W1, const float* __restrict__ b1,
    const float* __restrict__ W2, const float* __restrict__ b2,
    const float* __restrict__ W3, const float* __restrict__ b3,
    const float* __restrict__ Wg1, const float* __restrict__ bg1,
    const float* __restrict__ Wg2, const float* __restrict__ bg2,
    const unsigned int* __restrict__ mask_arr, char* __restrict__ img)
{
    const int t = threadIdx.x;
    const int bid = blockIdx.x;
    _Float16* H = (_Float16*)img;
    float* F = (float*)(img + OF32);

    if (bid == 0) {
        __shared__ unsigned red[256];
        unsigned um = 0u;
        for (int i = t; i < ADJ_BLOCKS; i += 256) um |= mask_arr[i];
        red[t] = um;
        __syncthreads();
        for (int s = 128; s > 0; s >>= 1) {
            if (t < s) red[t] |= red[t + s];
            __syncthreads();
        }
        const unsigned m = red[0];

        for (int i = t; i < 64; i += 256) F[FB2 + i] = b2[i];
        for (int i = t; i < 64; i += 256) F[FB3 + i] = b3[i];
        for (int i = t; i < 32; i += 256) {
            float s = 0.f;
            for (int h = 0; h < 64; ++h) s = fmaf(b3[h], Wg1[h * 32 + i], s);
            F[FB3G + i] = s;
        }
        for (int i = t; i < 32; i += 256) F[FBG1 + i] = bg1[i];
        for (int i = t; i < 128; i += 256) F[FWG2 + i] = Wg2[i];
        for (int i = t; i < 4; i += 256) F[FBG2 + i] = bg2[i];
        if (t == 0) {
            float A[4][4];
            for (int i = 0; i < 4; ++i)
                for (int j = 0; j < 4; ++j) A[i][j] = (i == j) ? 1.f : 0.f;
            int bit = 0;
            for (int i = 0; i < 4; ++i)
                for (int j = i + 1; j < 4; ++j) {
                    if ((m >> bit) & 1u) { A[i][j] = 1.f; A[j][i] = 1.f; }
                    ++bit;
                }
            float dinv[4];
            for (int i = 0; i < 4; ++i)
                dinv[i] = 1.0f / sqrtf(A[i][0] + A[i][1] + A[i][2] + A[i][3]);
            for (int i = 0; i < 4; ++i)
                for (int j = 0; j < 4; ++j) F[FAHAT + i * 4 + j] = dinv[i] * A[i][j] * dinv[j];
        }
    } else if (bid == 1) {
        for (int i = t; i < 128 * 40; i += 256) {
            int j = i / 40, kk = i % 40;
            float v = (kk < 4) ? W1[kk * 128 + j] : (kk == 4 ? b1[j] : 0.f);
            H[OW1E / 2 + i] = (_Float16)v;
        }
    } else if (bid == 2) {
        for (int i = t; i < 64 * 136; i += 256) {
            int jo = i / 136, ji = i % 136;
            H[OW2T / 2 + i] = (_Float16)(ji < 128 ? W2[ji * 64 + jo] : 0.f);
        }
    } else {
        for (int i = t; i < 64 * 72; i += 256) {
            int h = i / 72, j = i % 72;
            H[OW3T / 2 + i] = (_Float16)(j < 64 ? W3[j * 64 + h] : 0.f);
        }
        for (int i = t; i < 32 * 72; i += 256) {
            int e = i / 72, j = i % 72;
            float s = 0.f;
            if (j < 64)
                for (int h = 0; h < 64; ++h) s = fmaf(W3[j * 64 + h], Wg1[h * 32 + e], s);
            H[OW3GT / 2 + i] = (_Float16)s;
        }
    }
}

// ---------------------------------------------------------------------------
// helpers
// ---------------------------------------------------------------------------
__device__ __forceinline__ unsigned pkf16(float a, float b) {
    unsigned short ha = __builtin_bit_cast(unsigned short, (_Float16)a);
    unsigned short hb = __builtin_bit_cast(unsigned short, (_Float16)b);
    return (unsigned)ha | ((unsigned)hb << 16);
}
__device__ __forceinline__ f32x4 MF(f16x8 a, f16x8 b, f32x4 c) {
    return __builtin_amdgcn_mfma_f32_16x16x32_f16(a, b, c, 0, 0, 0);
}
__device__ __forceinline__ f16x8 ldA(const _Float16* p) {
    return *(const f16x8*)p;            // 16B-aligned ds_read_b128
}

// ---------------------------------------------------------------------------
// Kernel 3: fused MLP+GCN, f16 MFMA. 512 thr = 8 waves, 2 tiles/wave.
// R9: C->B repack via per-wave staged-LDS (write b64 in B-layout, read b64
// pairs) instead of ds_bpermute (192 pulls removed; pulls paid 2x for the
// hi/lo discard). Per-wave DS ops are in-order on the LDS pipe -> no
// barriers needed for the same-wave RAW/WAR. Tail reduce via permlane
// swaps (VALU) removes the last 32 LDS-pipe ops per tile.
// Staging math (mirrors the R3-verified buildB): value h[j][node] lives in
// C-frag lane(gw,cw)=((j&15)>>2, node&15) reg-pair p=(j&3)>>1; staged at
// sb[node][j'=(mt&1)*16+gw*4] (j = mt*16+gw*4+2p+bit, j' = j-32kt); B-frag
// lane(g,c) reads sb[nt*16+c][8g..8g+7] = act[node][32kt+8g+e]. ✓
// ---------------------------------------------------------------------------
__global__ __launch_bounds__(512, 2) void mlp_gcn_mfma(
    const float* __restrict__ x, const char* __restrict__ img,
    float* __restrict__ emb_out, float* __restrict__ out_out)
{
    __shared__ u32x4 smem4[SMEM_BYTES / 16];
    char* smem = (char*)smem4;
    const int tx = threadIdx.x;
    {   // stage weight image (flat, coalesced)
        const u32x4* src = (const u32x4*)img;
        u32x4* dst = (u32x4*)smem;
        for (int i = tx; i < IMG_BYTES / 16; i += 512) dst[i] = src[i];
    }
    __syncthreads();

    const _Float16* wh = (const _Float16*)smem;
    const float* wf = (const float*)(smem + OF32);

    const int wid = tx >> 6, lane = tx & 63;
    const int g = lane >> 4, c = lane & 15;
    const bool g0 = (g == 0);

    char* wb = smem + IMG_BYTES + wid * WBUF_BYTES;   // per-wave scratch
    _Float16* sb = (_Float16*)wb;                     // B-staging view
    float* tb = (float*)wb;                           // emb-transpose view

    // tail constants
    const f32x4 arow = *(const f32x4*)(wf + FAHAT + (c & 3) * 4);
    f32x4 bg1v[2];
    bg1v[0] = *(const f32x4*)(wf + FBG1 + g * 4);
    bg1v[1] = *(const f32x4*)(wf + FBG1 + 16 + g * 4);
    const f32x4 bg2v = *(const f32x4*)(wf + FBG2);
    f32x4 wg2v[2][4];
#pragma unroll
    for (int m = 0; m < 2; ++m)
#pragma unroll
        for (int r = 0; r < 4; ++r)
            wg2v[m][r] = *(const f32x4*)(wf + FWG2 + (m * 16 + g * 4 + r) * 4);

    const size_t nbase0 = ((size_t)blockIdx.x * NWAVE + wid) * 128;  // 2 tiles/wave
    f32x4 xv = *(const f32x4*)(x + (nbase0 + lane) * 4);   // prefetch it=0

#pragma unroll 1
    for (int it = 0; it < 2; ++it) {
        const size_t nbase = nbase0 + (size_t)it * 64;
        const size_t pn = (it < 1) ? (nbase + 64) : nbase;
        f32x4 xnext = *(const f32x4*)(x + (pn + lane) * 4);

        // ---- x -> staged B-layout: lane = node, write k0..7 (x,1.0,pad) ----
        {
            uint2 w0; w0.x = pkf16(xv.x, xv.y); w0.y = pkf16(xv.z, xv.w);
            uint2 w1; w1.x = 0x00003C00u; w1.y = 0u;        // f16 {1.0, 0}, {0,0}
            *(uint2*)(sb + lane * SB_STRIDE + 0) = w0;
            *(uint2*)(sb + lane * SB_STRIDE + 4) = w1;
        }
        f16x8 xB[4];
#pragma unroll
        for (int nt = 0; nt < 4; ++nt) {                    // read k0..7, mask g>0
            uint2 lo = *(const uint2*)(sb + (nt * 16 + c) * SB_STRIDE + 0);
            uint2 hi = *(const uint2*)(sb + (nt * 16 + c) * SB_STRIDE + 4);
            u32x4 t;
            t.x = g0 ? lo.x : 0u; t.y = g0 ? lo.y : 0u;
            t.z = g0 ? hi.x : 0u; t.w = 0u;
            xB[nt] = __builtin_bit_cast(f16x8, t);
        }

        // ---- L1+L2 interleaved per kt: h1 chunk -> stage -> L2 MFMAs ----
        f32x4 acc2[4][4];
#pragma unroll
        for (int mt = 0; mt < 4; ++mt) {
            f32x4 bv = *(const f32x4*)(wf + FB2 + mt * 16 + g * 4);
#pragma unroll
            for (int nt = 0; nt < 4; ++nt) acc2[mt][nt] = bv;
        }
#pragma unroll
        for (int kt = 0; kt < 4; ++kt) {
#pragma unroll
            for (int mt2 = 0; mt2 < 2; ++mt2) {             // L1: j = 32kt..+31
                const int mt = 2 * kt + mt2;
                f16x8 a = ldA(wh + OW1E / 2 + (mt * 16 + c) * 40 + g * 8);
#pragma unroll
                for (int nt = 0; nt < 4; ++nt) {
                    f32x4 z = {0.f, 0.f, 0.f, 0.f};
                    f32x4 t = MF(a, xB[nt], z);
                    uint2 w;
                    w.x = pkf16(fmaxf(t[0], 0.f), fmaxf(t[1], 0.f));
                    w.y = pkf16(fmaxf(t[2], 0.f), fmaxf(t[3], 0.f));
                    *(uint2*)(sb + (nt * 16 + c) * SB_STRIDE + mt2 * 16 + g * 4) = w;
                }
            }
            f16x8 bf[4];
#pragma unroll
            for (int nt = 0; nt < 4; ++nt) {                // B-frags for this kt
                uint2 lo = *(const uint2*)(sb + (nt * 16 + c) * SB_STRIDE + g * 8);
                uint2 hi = *(const uint2*)(sb + (nt * 16 + c) * SB_STRIDE + g * 8 + 4);
                u32x4 t; t.x = lo.x; t.y = lo.y; t.z = hi.x; t.w = hi.y;
                bf[nt] = __builtin_bit_cast(f16x8, t);
            }
#pragma unroll
            for (int mt = 0; mt < 4; ++mt) {                // L2 MFMAs
                f16x8 a = ldA(wh + OW2T / 2 + (mt * 16 + c) * 136 + kt * 32 + g * 8);
#pragma unroll
                for (int nt = 0; nt < 4; ++nt) acc2[mt][nt] = MF(a, bf[nt], acc2[mt][nt]);
            }
        }

        // ---- pack h2 (relu) -> frees acc2 pressure before L3 ----
        unsigned pk2a[4][4][2];
#pragma unroll
        for (int mt = 0; mt < 4; ++mt)
#pragma unroll
            for (int nt = 0; nt < 4; ++nt) {
                pk2a[mt][nt][0] = pkf16(fmaxf(acc2[mt][nt][0], 0.f), fmaxf(acc2[mt][nt][1], 0.f));
                pk2a[mt][nt][1] = pkf16(fmaxf(acc2[mt][nt][2], 0.f), fmaxf(acc2[mt][nt][3], 0.f));
            }

        // ---- L3 per kt: stage h2 chunk -> emb/tt MFMAs ----
        f32x4 acc3[4][4], acc4[2][4];
#pragma unroll
        for (int mt = 0; mt < 4; ++mt) {
            f32x4 bv = *(const f32x4*)(wf + FB3 + mt * 16 + g * 4);
#pragma unroll
            for (int nt = 0; nt < 4; ++nt) acc3[mt][nt] = bv;
        }
#pragma unroll
        for (int mt = 0; mt < 2; ++mt) {
            f32x4 bv = *(const f32x4*)(wf + FB3G + mt * 16 + g * 4);
#pragma unroll
            for (int nt = 0; nt < 4; ++nt) acc4[mt][nt] = bv;
        }
#pragma unroll
        for (int kt = 0; kt < 2; ++kt) {
#pragma unroll
            for (int mt2 = 0; mt2 < 2; ++mt2) {
                const int mt = 2 * kt + mt2;
#pragma unroll
                for (int nt = 0; nt < 4; ++nt) {
                    uint2 w; w.x = pk2a[mt][nt][0]; w.y = pk2a[mt][nt][1];
                    *(uint2*)(sb + (nt * 16 + c) * SB_STRIDE + mt2 * 16 + g * 4) = w;
                }
            }
            f16x8 bf[4];
#pragma unroll
            for (int nt = 0; nt < 4; ++nt) {
                uint2 lo = *(const uint2*)(sb + (nt * 16 + c) * SB_STRIDE + g * 8);
                uint2 hi = *(const uint2*)(sb + (nt * 16 + c) * SB_STRIDE + g * 8 + 4);
                u32x4 t; t.x = lo.x; t.y = lo.y; t.z = hi.x; t.w = hi.y;
                bf[nt] = __builtin_bit_cast(f16x8, t);
            }
#pragma unroll
            for (int mt = 0; mt < 4; ++mt) {
                f16x8 a = ldA(wh + OW3T / 2 + (mt * 16 + c) * 72 + kt * 32 + g * 8);
#pragma unroll
                for (int nt = 0; nt < 4; ++nt) acc3[mt][nt] = MF(a, bf[nt], acc3[mt][nt]);
            }
#pragma unroll
            for (int mt = 0; mt < 2; ++mt) {
                f16x8 a = ldA(wh + OW3GT / 2 + (mt * 16 + c) * 72 + kt * 32 + g * 8);
#pragma unroll
                for (int nt = 0; nt < 4; ++nt) acc4[mt][nt] = MF(a, bf[nt], acc4[mt][nt]);
            }
        }

        // ---- emb store via per-wave LDS transpose (R8-verified) ----
#pragma unroll
        for (int nt = 0; nt < 4; ++nt) {
#pragma unroll
            for (int mt = 0; mt < 4; ++mt) {
                int sl = (mt * 4 + g) ^ (c & 7);
                *(f32x4*)(tb + c * 64 + sl * 4) = acc3[mt][nt];
            }
            float* gp = emb_out + (nbase + nt * 16) * 64;
#pragma unroll
            for (int s = 0; s < 4; ++s) {
                int row = s * 4 + g;
                int sl = c ^ (row & 7);
                f32x4 q = *(const f32x4*)(tb + row * 64 + sl * 4);
                *(f32x4*)(gp + s * 256 + lane * 4) = q;
            }
        }

        // ---- GCN tail: qb (DPP) mixes + permlane-swap reductions (VALU) ----
#pragma unroll
        for (int nt = 0; nt < 4; ++nt) {
            float u[4] = {0.f, 0.f, 0.f, 0.f};
#pragma unroll
            for (int m = 0; m < 2; ++m)
#pragma unroll
                for (int r = 0; r < 4; ++r) {
                    float v = acc4[m][nt][r];
                    float s = bg1v[m][r];
                    s = fmaf(arow.x, qb<0>(v), s);
                    s = fmaf(arow.y, qb<1>(v), s);
                    s = fmaf(arow.z, qb<2>(v), s);
                    s = fmaf(arow.w, qb<3>(v), s);
                    s = fmaxf(s, 0.f);
                    u[0] = fmaf(s, wg2v[m][r].x, u[0]);
                    u[1] = fmaf(s, wg2v[m][r].y, u[1]);
                    u[2] = fmaf(s, wg2v[m][r].z, u[2]);
                    u[3] = fmaf(s, wg2v[m][r].w, u[3]);
                }
#pragma unroll
            for (int o = 0; o < 4; ++o)
                u[o] = sum_xor32(sum_xor16(u[o]));          // sum over 4 g-groups
            float ov[4];
#pragma unroll
            for (int o = 0; o < 4; ++o) {
                float s = bg2v[o];
                s = fmaf(arow.x, qb<0>(u[o]), s);
                s = fmaf(arow.y, qb<1>(u[o]), s);
                s = fmaf(arow.z, qb<2>(u[o]), s);
                s = fmaf(arow.w, qb<3>(u[o]), s);
                ov[o] = s;
            }
            if (g0) {
                f32x4 t; t.x = ov[0]; t.y = ov[1]; t.z = ov[2]; t.w = ov[3];
                *(f32x4*)(out_out + (nbase + nt * 16 + c) * 4) = t;
            }
        }

        xv = xnext;
    }
}

// ---------------------------------------------------------------------------
extern "C" void kernel_launch(void* const* d_in, const int* in_sizes, int n_in,
                              void* d_out, int out_size, void* d_ws, size_t ws_size,
                              hipStream_t stream) {
    const float* x   = (const float*)d_in[0];
    const float* W1  = (const float*)d_in[1];
    const float* b1  = (const float*)d_in[2];
    const float* W2  = (const float*)d_in[3];
    const float* b2  = (const float*)d_in[4];
    const float* W3  = (const float*)d_in[5];
    const float* b3  = (const float*)d_in[6];
    const float* Wg1 = (const float*)d_in[7];
    const float* bg1 = (const float*)d_in[8];
    const float* Wg2 = (const float*)d_in[9];
    const float* bg2 = (const float*)d_in[10];

    unsigned int* mask_arr = (unsigned int*)d_ws;          // 4096 words, all rewritten
    char* img = (char*)d_ws + 16640;                       // past mask array, 256-aligned

    float* emb_out = (float*)d_out;
    float* out_out = emb_out + EMB_ELEMS;

    adj_kernel<<<ADJ_BLOCKS, 256, 0, stream>>>(x, mask_arr);
    prep_kernel<<<4, 256, 0, stream>>>(W1, b1, W2, b2, W3, b3, Wg1, bg1, Wg2, bg2,
                                       mask_arr, img);
    mlp_gcn_mfma<<<NNODE / 1024, 512, 0, stream>>>(x, img, emb_out, out_out);
}

// Round 12
// 112.769 us; speedup vs baseline: 2.5074x; 1.0476x over previous
//
#include <hip/hip_runtime.h>

#define NB 262144
#define NNODE (NB * 4)
#define EMB_ELEMS ((size_t)NNODE * 64)
#define ADJ_BLOCKS (NNODE / 256)               // 4096

typedef __attribute__((ext_vector_type(8))) _Float16 f16x8;
typedef __attribute__((ext_vector_type(4))) float f32x4;
typedef __attribute__((ext_vector_type(4))) unsigned int u32x4;

// ---- weight-image layout (bytes), strides padded to 16B multiples ----
#define OW1E  0        // [128][40] f16 : W1^T ext (k0..3=W1, k4=b1, pad 0)
#define OW2T  10240    // [64][136] f16 : W2^T, k-cols PERMUTED by pi (see below)
#define OW3T  27648    // [64][72]  f16 : W3^T, k-cols PERMUTED by pi
#define OW3GT 36864    // [32][72]  f16 : (W3@Wg1)^T, k-cols PERMUTED by pi
#define OF32  41472    // f32 section
#define IMG_BYTES 42880
// f32 section offsets (floats)
#define FB2   0
#define FB3   64
#define FB3G  128
#define FBG1  160
#define FWG2  192      // [32][4]
#define FBG2  320
#define FAHAT 324      // [4][4]

#define NWAVE 8                                 // 512 threads
// Per-wave scratch: xB staging [64 node][36 f16] (R9-verified) and the 4KB
// f32 emb-transpose buffer (time-disjoint uses, same memory).
#define SB_STRIDE 36
#define WBUF_BYTES (64 * SB_STRIDE * 2)         // 4608
#define SMEM_BYTES (IMG_BYTES + NWAVE * WBUF_BYTES)  // 79744 <= 80KB -> 2 blk/CU

// pi: the k-permutation that makes MFMA C-frags directly consumable as the
// next layer's B-frags (validated by R11's emb PASS). Sum over k is
// permutation-invariant when applied to BOTH operands.
// B-frag lane(g,c) elem e naturally holds C rows {4g..4g+3} of halves
// mt2=(e>>2) -> pi(k=8g+e) = 16*(e>>2) + 4g + (e&3) within each 32-k tile.
__device__ __forceinline__ int kperm(int ji) {   // ji = image column index
    int kt = ji >> 5, r = ji & 31, g = r >> 3, e = r & 7;
    return kt * 32 + ((e >> 2) << 4) + (g << 2) + (e & 3);
}

template <int J>
__device__ __forceinline__ float qb(float v) {      // broadcast quad-lane J (DPP)
    constexpr int ctrl = J | (J << 2) | (J << 4) | (J << 6);
    int r = __builtin_amdgcn_update_dpp(0, __builtin_bit_cast(int, v), ctrl, 0xF, 0xF, true);
    return __builtin_bit_cast(float, r);
}

// ---------------------------------------------------------------------------
// Kernel 1: adjacency union. One thread per NODE; quad lanes = one sample.
// DPP broadcasts at FULL exec (R4 bug). Per-block mask -> own slot; prep
// block 0 OR-reduces (R8: no global atomic funnel).
// ---------------------------------------------------------------------------
__global__ __launch_bounds__(256) void adj_kernel(const float* __restrict__ x,
                                                  unsigned int* __restrict__ mask_arr) {
    __shared__ unsigned int smask;
    if (threadIdx.x == 0) smask = 0u;
    __syncthreads();

    const int t = blockIdx.x * 256 + threadIdx.x;
    const int c = t & 3;
    f32x4 v = *(const f32x4*)(x + (size_t)t * 4);
    float nn = sqrtf(v.x * v.x + v.y * v.y + v.z * v.z + v.w * v.w);
    float inv = 1.0f / fmaxf(nn, 1e-8f);

    unsigned int m = 0u;
#define DOTJ(J) do {                                                            \
        const float bx = qb<J>(v.x), by = qb<J>(v.y);                           \
        const float bz = qb<J>(v.z), bw = qb<J>(v.w);                           \
        const float bi = qb<J>(inv);                                            \
        const float d = v.x * bx + v.y * by + v.z * bz + v.w * bw;              \
        if ((int)((J) != c) & (int)(d * inv * bi > 0.5f)) {                     \
            const int i_ = c < (J) ? c : (J);                                   \
            const int j_ = c < (J) ? (J) : c;                                   \
            m |= 1u << (2 * i_ + j_ - 1 - (i_ >> 1));                           \
        }                                                                       \
    } while (0)
    DOTJ(0); DOTJ(1); DOTJ(2); DOTJ(3);
#undef DOTJ

    if (m) atomicOr(&smask, m);
    __syncthreads();
    if (threadIdx.x == 0) mask_arr[blockIdx.x] = smask;
}

// ---------------------------------------------------------------------------
// Kernel 2: build f16 weight image (k-permuted) + f32 biases/Ahat. 4 blocks.
// ---------------------------------------------------------------------------
__global__ __launch_bounds__(256) void prep_kernel(
    const float* __restrict__ W1, const float* __restrict__ b1,
    const float* __restrict__ W2, const float* __restrict__ b2,
    const float* __restrict__ W3, const float* __restrict__ b3,
    const float* __restrict__ Wg1, const float* __restrict__ bg1,
    const float* __restrict__ Wg2, const float* __restrict__ bg2,
    const unsigned int* __restrict__ mask_arr, char* __restrict__ img)
{
    const int t = threadIdx.x;
    const int bid = blockIdx.x;
    _Float16* H = (_Float16*)img;
    float* F = (float*)(img + OF32);

    if (bid == 0) {
        __shared__ unsigned red[256];
        unsigned um = 0u;
        for (int i = t; i < ADJ_BLOCKS; i += 256) um |= mask_arr[i];
        red[t] = um;
        __syncthreads();
        for (int s = 128; s > 0; s >>= 1) {
            if (t < s) red[t] |= red[t + s];
            __syncthreads();
        }
        const unsigned m = red[0];

        for (int i = t; i < 64; i += 256) F[FB2 + i] = b2[i];
        for (int i = t; i < 64; i += 256) F[FB3 + i] = b3[i];
        for (int i = t; i < 32; i += 256) {
            float s = 0.f;
            for (int h = 0; h < 64; ++h) s = fmaf(b3[h], Wg1[h * 32 + i], s);
            F[FB3G + i] = s;
        }
        for (int i = t; i < 32; i += 256) F[FBG1 + i] = bg1[i];
        for (int i = t; i < 128; i += 256) F[FWG2 + i] = Wg2[i];
        for (int i = t; i < 4; i += 256) F[FBG2 + i] = bg2[i];
        if (t == 0) {
            float A[4][4];
            for (int i = 0; i < 4; ++i)
                for (int j = 0; j < 4; ++j) A[i][j] = (i == j) ? 1.f : 0.f;
            int bit = 0;
            for (int i = 0; i < 4; ++i)
                for (int j = i + 1; j < 4; ++j) {
                    if ((m >> bit) & 1u) { A[i][j] = 1.f; A[j][i] = 1.f; }
                    ++bit;
                }
            float dinv[4];
            for (int i = 0; i < 4; ++i)
                dinv[i] = 1.0f / sqrtf(A[i][0] + A[i][1] + A[i][2] + A[i][3]);
            for (int i = 0; i < 4; ++i)
                for (int j = 0; j < 4; ++j) F[FAHAT + i * 4 + j] = dinv[i] * A[i][j] * dinv[j];
        }
    } else if (bid == 1) {
        for (int i = t; i < 128 * 40; i += 256) {           // W1E (k = f, identity)
            int j = i / 40, kk = i % 40;
            float v = (kk < 4) ? W1[kk * 128 + j] : (kk == 4 ? b1[j] : 0.f);
            H[OW1E / 2 + i] = (_Float16)v;
        }
    } else if (bid == 2) {
        for (int i = t; i < 64 * 136; i += 256) {           // W2T, k-cols pi-permuted
            int jo = i / 136, ji = i % 136;
            float v = 0.f;
            if (ji < 128) v = W2[kperm(ji) * 64 + jo];
            H[OW2T / 2 + i] = (_Float16)v;
        }
    } else {
        for (int i = t; i < 64 * 72; i += 256) {            // W3T, k-cols pi-permuted
            int h = i / 72, j = i % 72;
            float v = 0.f;
            if (j < 64) v = W3[kperm(j) * 64 + h];
            H[OW3T / 2 + i] = (_Float16)v;
        }
        for (int i = t; i < 32 * 72; i += 256) {            // W3GT, k-cols pi-permuted
            int e = i / 72, j = i % 72;
            float s = 0.f;
            if (j < 64) {
                const int jj = kperm(j);
                for (int h = 0; h < 64; ++h) s = fmaf(W3[jj * 64 + h], Wg1[h * 32 + e], s);
            }
            H[OW3GT / 2 + i] = (_Float16)s;
        }
    }
}

// ---------------------------------------------------------------------------
// helpers
// ---------------------------------------------------------------------------
__device__ __forceinline__ unsigned pkf16(float a, float b) {
    unsigned short ha = __builtin_bit_cast(unsigned short, (_Float16)a);
    unsigned short hb = __builtin_bit_cast(unsigned short, (_Float16)b);
    return (unsigned)ha | ((unsigned)hb << 16);
}
__device__ __forceinline__ f32x4 MF(f16x8 a, f16x8 b, f32x4 c) {
    return __builtin_amdgcn_mfma_f32_16x16x32_f16(a, b, c, 0, 0, 0);
}
__device__ __forceinline__ f16x8 ldA(const _Float16* p) {
    return *(const f16x8*)p;            // 16B-aligned ds_read_b128
}
// B-frag = direct register concat of the two packed C-frag halves (valid
// because the weight image's k-columns are pi-permuted to match).
// Validated by R11's emb PASS.
__device__ __forceinline__ f16x8 bcat(unsigned X0, unsigned X1,
                                      unsigned Y0, unsigned Y1) {
    u32x4 t; t.x = X0; t.y = X1; t.z = Y0; t.w = Y1;
    return __builtin_bit_cast(f16x8, t);
}

// ---------------------------------------------------------------------------
// Kernel 3: fused MLP+GCN, f16 MFMA. 512 thr = 8 waves, 2 tiles/wave.
// R12: keep R11's pi-permuted weights + bcat (emb-validated, zero repack
// ops). Tail reduction reverted to __shfl_xor (R3-R8-validated) — R11's
// v_permlane*_swap inline asm corrupted the out-path reduction in this
// compilation context (coalescible "+v" operands / scheduling hazard;
// direction semantics never HW-probed). No permlane asm anywhere now.
// ---------------------------------------------------------------------------
__global__ __launch_bounds__(512, 2) void mlp_gcn_mfma(
    const float* __restrict__ x, const char* __restrict__ img,
    float* __restrict__ emb_out, float* __restrict__ out_out)
{
    __shared__ u32x4 smem4[SMEM_BYTES / 16];
    char* smem = (char*)smem4;
    const int tx = threadIdx.x;
    {   // stage weight image (flat, coalesced)
        const u32x4* src = (const u32x4*)img;
        u32x4* dst = (u32x4*)smem;
        for (int i = tx; i < IMG_BYTES / 16; i += 512) dst[i] = src[i];
    }
    __syncthreads();

    const _Float16* wh = (const _Float16*)smem;
    const float* wf = (const float*)(smem + OF32);

    const int wid = tx >> 6, lane = tx & 63;
    const int g = lane >> 4, c = lane & 15;
    const bool g0 = (g == 0);

    char* wb = smem + IMG_BYTES + wid * WBUF_BYTES;   // per-wave scratch
    _Float16* sb = (_Float16*)wb;                     // xB staging view
    float* tb = (float*)wb;                           // emb-transpose view

    // tail constants
    const f32x4 arow = *(const f32x4*)(wf + FAHAT + (c & 3) * 4);
    f32x4 bg1v[2];
    bg1v[0] = *(const f32x4*)(wf + FBG1 + g * 4);
    bg1v[1] = *(const f32x4*)(wf + FBG1 + 16 + g * 4);
    const f32x4 bg2v = *(const f32x4*)(wf + FBG2);
    f32x4 wg2v[2][4];
#pragma unroll
    for (int m = 0; m < 2; ++m)
#pragma unroll
        for (int r = 0; r < 4; ++r)
            wg2v[m][r] = *(const f32x4*)(wf + FWG2 + (m * 16 + g * 4 + r) * 4);

    const size_t nbase0 = ((size_t)blockIdx.x * NWAVE + wid) * 128;  // 2 tiles/wave
    f32x4 xv = *(const f32x4*)(x + (nbase0 + lane) * 4);   // prefetch it=0

#pragma unroll 1
    for (int it = 0; it < 2; ++it) {
        const size_t nbase = nbase0 + (size_t)it * 64;
        const size_t pn = (it < 1) ? (nbase + 64) : nbase;
        f32x4 xnext = *(const f32x4*)(x + (pn + lane) * 4);

        // ---- x -> xB frags via tiny LDS stage (R9-verified layout) ----
        {
            uint2 w0; w0.x = pkf16(xv.x, xv.y); w0.y = pkf16(xv.z, xv.w);
            uint2 w1; w1.x = 0x00003C00u; w1.y = 0u;        // f16 {1.0, 0}, {0,0}
            *(uint2*)(sb + lane * SB_STRIDE + 0) = w0;
            *(uint2*)(sb + lane * SB_STRIDE + 4) = w1;
        }
        f16x8 xB[4];
#pragma unroll
        for (int nt = 0; nt < 4; ++nt) {                    // read k0..7, mask g>0
            uint2 lo = *(const uint2*)(sb + (nt * 16 + c) * SB_STRIDE + 0);
            uint2 hi = *(const uint2*)(sb + (nt * 16 + c) * SB_STRIDE + 4);
            u32x4 t;
            t.x = g0 ? lo.x : 0u; t.y = g0 ? lo.y : 0u;
            t.z = g0 ? hi.x : 0u; t.w = 0u;
            xB[nt] = __builtin_bit_cast(f16x8, t);
        }

        // ---- L1+L2 per kt: h1 chunk -> direct-concat B-frags -> L2 MFMAs ----
        f32x4 acc2[4][4];
#pragma unroll
        for (int mt = 0; mt < 4; ++mt) {
            f32x4 bv = *(const f32x4*)(wf + FB2 + mt * 16 + g * 4);
#pragma unroll
            for (int nt = 0; nt < 4; ++nt) acc2[mt][nt] = bv;
        }
#pragma unroll
        for (int kt = 0; kt < 4; ++kt) {
            f16x8 a0 = ldA(wh + OW1E / 2 + ((2 * kt + 0) * 16 + c) * 40 + g * 8);
            f16x8 a1 = ldA(wh + OW1E / 2 + ((2 * kt + 1) * 16 + c) * 40 + g * 8);
            f16x8 bf[4];
#pragma unroll
            for (int nt = 0; nt < 4; ++nt) {
                f32x4 z = {0.f, 0.f, 0.f, 0.f};
                f32x4 t0 = MF(a0, xB[nt], z);
                f32x4 t1 = MF(a1, xB[nt], z);
                bf[nt] = bcat(pkf16(fmaxf(t0[0], 0.f), fmaxf(t0[1], 0.f)),
                              pkf16(fmaxf(t0[2], 0.f), fmaxf(t0[3], 0.f)),
                              pkf16(fmaxf(t1[0], 0.f), fmaxf(t1[1], 0.f)),
                              pkf16(fmaxf(t1[2], 0.f), fmaxf(t1[3], 0.f)));
            }
#pragma unroll
            for (int mt = 0; mt < 4; ++mt) {                // L2 MFMAs
                f16x8 a = ldA(wh + OW2T / 2 + (mt * 16 + c) * 136 + kt * 32 + g * 8);
#pragma unroll
                for (int nt = 0; nt < 4; ++nt) acc2[mt][nt] = MF(a, bf[nt], acc2[mt][nt]);
            }
        }

        // ---- pack h2 (relu) ----
        unsigned pk2a[4][4][2];
#pragma unroll
        for (int mt = 0; mt < 4; ++mt)
#pragma unroll
            for (int nt = 0; nt < 4; ++nt) {
                pk2a[mt][nt][0] = pkf16(fmaxf(acc2[mt][nt][0], 0.f), fmaxf(acc2[mt][nt][1], 0.f));
                pk2a[mt][nt][1] = pkf16(fmaxf(acc2[mt][nt][2], 0.f), fmaxf(acc2[mt][nt][3], 0.f));
            }

        // ---- L3 per kt: direct-concat B-frags -> emb/tt MFMAs ----
        f32x4 acc3[4][4], acc4[2][4];
#pragma unroll
        for (int mt = 0; mt < 4; ++mt) {
            f32x4 bv = *(const f32x4*)(wf + FB3 + mt * 16 + g * 4);
#pragma unroll
            for (int nt = 0; nt < 4; ++nt) acc3[mt][nt] = bv;
        }
#pragma unroll
        for (int mt = 0; mt < 2; ++mt) {
            f32x4 bv = *(const f32x4*)(wf + FB3G + mt * 16 + g * 4);
#pragma unroll
            for (int nt = 0; nt < 4; ++nt) acc4[mt][nt] = bv;
        }
#pragma unroll
        for (int kt = 0; kt < 2; ++kt) {
            f16x8 bf[4];
#pragma unroll
            for (int nt = 0; nt < 4; ++nt)
                bf[nt] = bcat(pk2a[2 * kt][nt][0], pk2a[2 * kt][nt][1],
                              pk2a[2 * kt + 1][nt][0], pk2a[2 * kt + 1][nt][1]);
#pragma unroll
            for (int mt = 0; mt < 4; ++mt) {
                f16x8 a = ldA(wh + OW3T / 2 + (mt * 16 + c) * 72 + kt * 32 + g * 8);
#pragma unroll
                for (int nt = 0; nt < 4; ++nt) acc3[mt][nt] = MF(a, bf[nt], acc3[mt][nt]);
            }
#pragma unroll
            for (int mt = 0; mt < 2; ++mt) {
                f16x8 a = ldA(wh + OW3GT / 2 + (mt * 16 + c) * 72 + kt * 32 + g * 8);
#pragma unroll
                for (int nt = 0; nt < 4; ++nt) acc4[mt][nt] = MF(a, bf[nt], acc4[mt][nt]);
            }
        }

        // ---- emb store via per-wave LDS transpose (R8-verified) ----
#pragma unroll
        for (int nt = 0; nt < 4; ++nt) {
#pragma unroll
            for (int mt = 0; mt < 4; ++mt) {
                int sl = (mt * 4 + g) ^ (c & 7);
                *(f32x4*)(tb + c * 64 + sl * 4) = acc3[mt][nt];
            }
            float* gp = emb_out + (nbase + nt * 16) * 64;
#pragma unroll
            for (int s = 0; s < 4; ++s) {
                int row = s * 4 + g;
                int sl = c ^ (row & 7);
                f32x4 q = *(const f32x4*)(tb + row * 64 + sl * 4);
                *(f32x4*)(gp + s * 256 + lane * 4) = q;
            }
        }

        // ---- GCN tail: qb (DPP) mixes + __shfl_xor reductions (R3-R8 path) ----
#pragma unroll
        for (int nt = 0; nt < 4; ++nt) {
            float u[4] = {0.f, 0.f, 0.f, 0.f};
#pragma unroll
            for (int m = 0; m < 2; ++m)
#pragma unroll
                for (int r = 0; r < 4; ++r) {
                    float v = acc4[m][nt][r];
                    float s = bg1v[m][r];
                    s = fmaf(arow.x, qb<0>(v), s);
                    s = fmaf(arow.y, qb<1>(v), s);
                    s = fmaf(arow.z, qb<2>(v), s);
                    s = fmaf(arow.w, qb<3>(v), s);
                    s = fmaxf(s, 0.f);
                    u[0] = fmaf(s, wg2v[m][r].x, u[0]);
                    u[1] = fmaf(s, wg2v[m][r].y, u[1]);
                    u[2] = fmaf(s, wg2v[m][r].z, u[2]);
                    u[3] = fmaf(s, wg2v[m][r].w, u[3]);
                }
#pragma unroll
            for (int o = 0; o < 4; ++o) {
                u[o] += __shfl_xor(u[o], 16);
                u[o] += __shfl_xor(u[o], 32);
            }
            float ov[4];
#pragma unroll
            for (int o = 0; o < 4; ++o) {
                float s = bg2v[o];
                s = fmaf(arow.x, qb<0>(u[o]), s);
                s = fmaf(arow.y, qb<1>(u[o]), s);
                s = fmaf(arow.z, qb<2>(u[o]), s);
                s = fmaf(arow.w, qb<3>(u[o]), s);
                ov[o] = s;
            }
            if (g0) {
                f32x4 t; t.x = ov[0]; t.y = ov[1]; t.z = ov[2]; t.w = ov[3];
                *(f32x4*)(out_out + (nbase + nt * 16 + c) * 4) = t;
            }
        }

        xv = xnext;
    }
}

// ---------------------------------------------------------------------------
extern "C" void kernel_launch(void* const* d_in, const int* in_sizes, int n_in,
                              void* d_out, int out_size, void* d_ws, size_t ws_size,
                              hipStream_t stream) {
    const float* x   = (const float*)d_in[0];
    const float* W1  = (const float*)d_in[1];
    const float* b1  = (const float*)d_in[2];
    const float* W2  = (const float*)d_in[3];
    const float* b2  = (const float*)d_in[4];
    const float* W3  = (const float*)d_in[5];
    const float* b3  = (const float*)d_in[6];
    const float* Wg1 = (const float*)d_in[7];
    const float* bg1 = (const float*)d_in[8];
    const float* Wg2 = (const float*)d_in[9];
    const float* bg2 = (const float*)d_in[10];

    unsigned int* mask_arr = (unsigned int*)d_ws;          // 4096 words, all rewritten
    char* img = (char*)d_ws + 16640;                       // past mask array, 256-aligned

    float* emb_out = (float*)d_out;
    float* out_out = emb_out + EMB_ELEMS;

    adj_kernel<<<ADJ_BLOCKS, 256, 0, stream>>>(x, mask_arr);
    prep_kernel<<<4, 256, 0, stream>>>(W1, b1, W2, b2, W3, b3, Wg1, bg1, Wg2, bg2,
                                       mask_arr, img);
    mlp_gcn_mfma<<<NNODE / 1024, 512, 0, stream>>>(x, img, emb_out, out_out);
}

// Round 13
// 111.782 us; speedup vs baseline: 2.5296x; 1.0088x over previous
//
#include <hip/hip_runtime.h>

#define NB 262144
#define NNODE (NB * 4)
#define EMB_ELEMS ((size_t)NNODE * 64)
#define ADJ_BLOCKS (NNODE / 256)               // 4096

typedef __attribute__((ext_vector_type(8))) _Float16 f16x8;
typedef __attribute__((ext_vector_type(4))) float f32x4;
typedef __attribute__((ext_vector_type(4))) unsigned int u32x4;

// ---- weight-image layout (bytes), strides padded to 16B multiples ----
#define OW1E  0        // [128][40] f16 : W1^T ext (k0..3=W1, k4=b1, pad 0)
#define OW2T  10240    // [64][136] f16 : W2^T, k-cols PERMUTED by pi
#define OW3T  27648    // [64][72]  f16 : W3^T, k-cols PERMUTED by pi
#define OW3GT 36864    // [32][72]  f16 : (W3@Wg1)^T, k-cols PERMUTED by pi
#define OWG2A 41472    // [16][40]  f16 : Wg2^T pi-permuted A-tile (rows 4..15 = 0)
#define OF32  42752    // f32 section
#define IMG_BYTES 43600
// f32 section offsets (floats)
#define FB2   0
#define FB3   64
#define FB3G  128
#define FBG1  160
#define FBG2  192
#define FAHAT 196      // [4][4]

#define NWAVE 8                                 // 512 threads
#define WBUF_BYTES 4096                         // per-wave f32 emb-transpose buffer
#define SMEM_BYTES (IMG_BYTES + NWAVE * WBUF_BYTES)  // 76368 -> 2 blk/CU

// pi: k-permutation making MFMA C-frags directly consumable as B-frags
// (validated end-to-end by R11 emb / R12 full pass).
// pi(ji): kt=ji>>5, r=ji&31, g=r>>3, e=r&7 -> kt*32 + 16*(e>>2) + 4g + (e&3).
__device__ __forceinline__ int kperm(int ji) {
    int kt = ji >> 5, r = ji & 31, g = r >> 3, e = r & 7;
    return kt * 32 + ((e >> 2) << 4) + (g << 2) + (e & 3);
}

template <int J>
__device__ __forceinline__ float qb(float v) {      // broadcast quad-lane J (DPP)
    constexpr int ctrl = J | (J << 2) | (J << 4) | (J << 6);
    int r = __builtin_amdgcn_update_dpp(0, __builtin_bit_cast(int, v), ctrl, 0xF, 0xF, true);
    return __builtin_bit_cast(float, r);
}

// ---------------------------------------------------------------------------
// Kernel 1: adjacency union. One thread per NODE; quad lanes = one sample.
// DPP broadcasts at FULL exec (R4 bug). Per-block mask -> own slot; prep
// block 0 OR-reduces (R8: no global atomic funnel).
// ---------------------------------------------------------------------------
__global__ __launch_bounds__(256) void adj_kernel(const float* __restrict__ x,
                                                  unsigned int* __restrict__ mask_arr) {
    __shared__ unsigned int smask;
    if (threadIdx.x == 0) smask = 0u;
    __syncthreads();

    const int t = blockIdx.x * 256 + threadIdx.x;
    const int c = t & 3;
    f32x4 v = *(const f32x4*)(x + (size_t)t * 4);
    float nn = sqrtf(v.x * v.x + v.y * v.y + v.z * v.z + v.w * v.w);
    float inv = 1.0f / fmaxf(nn, 1e-8f);

    unsigned int m = 0u;
#define DOTJ(J) do {                                                            \
        const float bx = qb<J>(v.x), by = qb<J>(v.y);                           \
        const float bz = qb<J>(v.z), bw = qb<J>(v.w);                           \
        const float bi = qb<J>(inv);                                            \
        const float d = v.x * bx + v.y * by + v.z * bz + v.w * bw;              \
        if ((int)((J) != c) & (int)(d * inv * bi > 0.5f)) {                     \
            const int i_ = c < (J) ? c : (J);                                   \
            const int j_ = c < (J) ? (J) : c;                                   \
            m |= 1u << (2 * i_ + j_ - 1 - (i_ >> 1));                           \
        }                                                                       \
    } while (0)
    DOTJ(0); DOTJ(1); DOTJ(2); DOTJ(3);
#undef DOTJ

    if (m) atomicOr(&smask, m);
    __syncthreads();
    if (threadIdx.x == 0) mask_arr[blockIdx.x] = smask;
}

// ---------------------------------------------------------------------------
// Kernel 2: build f16 weight image (k-permuted) + f32 biases/Ahat. 4 blocks.
// ---------------------------------------------------------------------------
__global__ __launch_bounds__(256) void prep_kernel(
    const float* __restrict__ W1, const float* __restrict__ b1,
    const float* __restrict__ W2, const float* __restrict__ b2,
    const float* __restrict__ W3, const float* __restrict__ b3,
    const float* __restrict__ Wg1, const float* __restrict__ bg1,
    const float* __restrict__ Wg2, const float* __restrict__ bg2,
    const unsigned int* __restrict__ mask_arr, char* __restrict__ img)
{
    const int t = threadIdx.x;
    const int bid = blockIdx.x;
    _Float16* H = (_Float16*)img;
    float* F = (float*)(img + OF32);

    if (bid == 0) {
        __shared__ unsigned red[256];
        unsigned um = 0u;
        for (int i = t; i < ADJ_BLOCKS; i += 256) um |= mask_arr[i];
        red[t] = um;
        __syncthreads();
        for (int s = 128; s > 0; s >>= 1) {
            if (t < s) red[t] |= red[t + s];
            __syncthreads();
        }
        const unsigned m = red[0];

        for (int i = t; i < 64; i += 256) F[FB2 + i] = b2[i];
        for (int i = t; i < 64; i += 256) F[FB3 + i] = b3[i];
        for (int i = t; i < 32; i += 256) {
            float s = 0.f;
            for (int h = 0; h < 64; ++h) s = fmaf(b3[h], Wg1[h * 32 + i], s);
            F[FB3G + i] = s;
        }
        for (int i = t; i < 32; i += 256) F[FBG1 + i] = bg1[i];
        for (int i = t; i < 4; i += 256) F[FBG2 + i] = bg2[i];
        for (int i = t; i < 16 * 40; i += 256) {            // OWG2A: Wg2^T pi-perm
            int o = i / 40, ji = i % 40;
            float v = (o < 4 && ji < 32) ? Wg2[kperm(ji) * 4 + o] : 0.f;
            H[OWG2A / 2 + i] = (_Float16)v;
        }
        if (t == 0) {
            float A[4][4];
            for (int i = 0; i < 4; ++i)
                for (int j = 0; j < 4; ++j) A[i][j] = (i == j) ? 1.f : 0.f;
            int bit = 0;
            for (int i = 0; i < 4; ++i)
                for (int j = i + 1; j < 4; ++j) {
                    if ((m >> bit) & 1u) { A[i][j] = 1.f; A[j][i] = 1.f; }
                    ++bit;
                }
            float dinv[4];
            for (int i = 0; i < 4; ++i)
                dinv[i] = 1.0f / sqrtf(A[i][0] + A[i][1] + A[i][2] + A[i][3]);
            for (int i = 0; i < 4; ++i)
                for (int j = 0; j < 4; ++j) F[FAHAT + i * 4 + j] = dinv[i] * A[i][j] * dinv[j];
        }
    } else if (bid == 1) {
        for (int i = t; i < 128 * 40; i += 256) {           // W1E (k identity)
            int j = i / 40, kk = i % 40;
            float v = (kk < 4) ? W1[kk * 128 + j] : (kk == 4 ? b1[j] : 0.f);
            H[OW1E / 2 + i] = (_Float16)v;
        }
    } else if (bid == 2) {
        for (int i = t; i < 64 * 136; i += 256) {           // W2T, k-cols pi-perm
            int jo = i / 136, ji = i % 136;
            float v = 0.f;
            if (ji < 128) v = W2[kperm(ji) * 64 + jo];
            H[OW2T / 2 + i] = (_Float16)v;
        }
    } else {
        for (int i = t; i < 64 * 72; i += 256) {            // W3T, k-cols pi-perm
            int h = i / 72, j = i % 72;
            float v = 0.f;
            if (j < 64) v = W3[kperm(j) * 64 + h];
            H[OW3T / 2 + i] = (_Float16)v;
        }
        for (int i = t; i < 32 * 72; i += 256) {            // W3GT, k-cols pi-perm
            int e = i / 72, j = i % 72;
            float s = 0.f;
            if (j < 64) {
                const int jj = kperm(j);
                for (int h = 0; h < 64; ++h) s = fmaf(W3[jj * 64 + h], Wg1[h * 32 + e], s);
            }
            H[OW3GT / 2 + i] = (_Float16)s;
        }
    }
}

// ---------------------------------------------------------------------------
// helpers
// ---------------------------------------------------------------------------
__device__ __forceinline__ unsigned pkf16(float a, float b) {
    unsigned short ha = __builtin_bit_cast(unsigned short, (_Float16)a);
    unsigned short hb = __builtin_bit_cast(unsigned short, (_Float16)b);
    return (unsigned)ha | ((unsigned)hb << 16);
}
__device__ __forceinline__ f32x4 MF(f16x8 a, f16x8 b, f32x4 c) {
    return __builtin_amdgcn_mfma_f32_16x16x32_f16(a, b, c, 0, 0, 0);
}
__device__ __forceinline__ f16x8 ldA(const _Float16* p) {
    return *(const f16x8*)p;            // 16B-aligned ds_read_b128
}
// B-frag = direct register concat of packed C-frag halves (weights are
// pi-permuted to match). Validated R11/R12.
__device__ __forceinline__ f16x8 bcat(unsigned X0, unsigned X1,
                                      unsigned Y0, unsigned Y1) {
    u32x4 t; t.x = X0; t.y = X1; t.z = Y0; t.w = Y1;
    return __builtin_bit_cast(f16x8, t);
}

// ---------------------------------------------------------------------------
// Kernel 3: fused MLP+GCN, f16 MFMA. 512 thr = 8 waves, 2 tiles/wave.
// R13: (a) xB via direct global loads (no LDS staging round-trip, no WAR
// with the transpose buffer); (b) tail Wg2 contraction as one pi-permuted
// MFMA per nt (bcat pattern, R11/R12-validated) — ZERO shuffles/swizzles
// remain; (c) tail runs before the emb transpose so out/emb stores drain
// under the next tile's compute.
// ---------------------------------------------------------------------------
__global__ __launch_bounds__(512, 2) void mlp_gcn_mfma(
    const float* __restrict__ x, const char* __restrict__ img,
    float* __restrict__ emb_out, float* __restrict__ out_out)
{
    __shared__ u32x4 smem4[SMEM_BYTES / 16];
    char* smem = (char*)smem4;
    const int tx = threadIdx.x;
    {   // stage weight image (flat, coalesced)
        const u32x4* src = (const u32x4*)img;
        u32x4* dst = (u32x4*)smem;
        for (int i = tx; i < IMG_BYTES / 16; i += 512) dst[i] = src[i];
    }
    __syncthreads();

    const _Float16* wh = (const _Float16*)smem;
    const float* wf = (const float*)(smem + OF32);

    const int wid = tx >> 6, lane = tx & 63;
    const int g = lane >> 4, c = lane & 15;
    const bool g0 = (g == 0);

    float* tb = (float*)(smem + IMG_BYTES) + wid * 1024;   // 4KB/wave transpose buf

    // tile-invariant constants
    const f32x4 arow = *(const f32x4*)(wf + FAHAT + (c & 3) * 4);
    f32x4 bg1v[2];
    bg1v[0] = *(const f32x4*)(wf + FBG1 + g * 4);
    bg1v[1] = *(const f32x4*)(wf + FBG1 + 16 + g * 4);
    const f32x4 bg2v = *(const f32x4*)(wf + FBG2);
    const f16x8 aWg2 = ldA(wh + OWG2A / 2 + c * 40 + g * 8);   // out-MFMA A-frag

    const size_t nbase0 = ((size_t)blockIdx.x * NWAVE + wid) * 128;  // 2 tiles/wave

#pragma unroll 1
    for (int it = 0; it < 2; ++it) {
        const size_t nbase = nbase0 + (size_t)it * 64;

        // ---- xB frags via direct global loads (g-redundant, L1-served) ----
        f16x8 xB[4];
#pragma unroll
        for (int nt = 0; nt < 4; ++nt) {
            f32x4 xq = *(const f32x4*)(x + (nbase + nt * 16 + c) * 4);
            u32x4 t;
            t.x = g0 ? pkf16(xq.x, xq.y) : 0u;
            t.y = g0 ? pkf16(xq.z, xq.w) : 0u;
            t.z = g0 ? 0x00003C00u : 0u;    // f16 {1.0, 0}
            t.w = 0u;
            xB[nt] = __builtin_bit_cast(f16x8, t);
        }

        // ---- L1+L2 per kt: h1 chunk -> bcat B-frags -> L2 MFMAs ----
        f32x4 acc2[4][4];
#pragma unroll
        for (int mt = 0; mt < 4; ++mt) {
            f32x4 bv = *(const f32x4*)(wf + FB2 + mt * 16 + g * 4);
#pragma unroll
            for (int nt = 0; nt < 4; ++nt) acc2[mt][nt] = bv;
        }
#pragma unroll
        for (int kt = 0; kt < 4; ++kt) {
            f16x8 a0 = ldA(wh + OW1E / 2 + ((2 * kt + 0) * 16 + c) * 40 + g * 8);
            f16x8 a1 = ldA(wh + OW1E / 2 + ((2 * kt + 1) * 16 + c) * 40 + g * 8);
            f16x8 bf[4];
#pragma unroll
            for (int nt = 0; nt < 4; ++nt) {
                f32x4 z = {0.f, 0.f, 0.f, 0.f};
                f32x4 t0 = MF(a0, xB[nt], z);
                f32x4 t1 = MF(a1, xB[nt], z);
                bf[nt] = bcat(pkf16(fmaxf(t0[0], 0.f), fmaxf(t0[1], 0.f)),
                              pkf16(fmaxf(t0[2], 0.f), fmaxf(t0[3], 0.f)),
                              pkf16(fmaxf(t1[0], 0.f), fmaxf(t1[1], 0.f)),
                              pkf16(fmaxf(t1[2], 0.f), fmaxf(t1[3], 0.f)));
            }
#pragma unroll
            for (int mt = 0; mt < 4; ++mt) {
                f16x8 a = ldA(wh + OW2T / 2 + (mt * 16 + c) * 136 + kt * 32 + g * 8);
#pragma unroll
                for (int nt = 0; nt < 4; ++nt) acc2[mt][nt] = MF(a, bf[nt], acc2[mt][nt]);
            }
        }

        // ---- pack h2 (relu) ----
        unsigned pk2a[4][4][2];
#pragma unroll
        for (int mt = 0; mt < 4; ++mt)
#pragma unroll
            for (int nt = 0; nt < 4; ++nt) {
                pk2a[mt][nt][0] = pkf16(fmaxf(acc2[mt][nt][0], 0.f), fmaxf(acc2[mt][nt][1], 0.f));
                pk2a[mt][nt][1] = pkf16(fmaxf(acc2[mt][nt][2], 0.f), fmaxf(acc2[mt][nt][3], 0.f));
            }

        // ---- L3 per kt: bcat B-frags -> emb/tt MFMAs ----
        f32x4 acc3[4][4], acc4[2][4];
#pragma unroll
        for (int mt = 0; mt < 4; ++mt) {
            f32x4 bv = *(const f32x4*)(wf + FB3 + mt * 16 + g * 4);
#pragma unroll
            for (int nt = 0; nt < 4; ++nt) acc3[mt][nt] = bv;
        }
#pragma unroll
        for (int mt = 0; mt < 2; ++mt) {
            f32x4 bv = *(const f32x4*)(wf + FB3G + mt * 16 + g * 4);
#pragma unroll
            for (int nt = 0; nt < 4; ++nt) acc4[mt][nt] = bv;
        }
#pragma unroll
        for (int kt = 0; kt < 2; ++kt) {
            f16x8 bf[4];
#pragma unroll
            for (int nt = 0; nt < 4; ++nt)
                bf[nt] = bcat(pk2a[2 * kt][nt][0], pk2a[2 * kt][nt][1],
                              pk2a[2 * kt + 1][nt][0], pk2a[2 * kt + 1][nt][1]);
#pragma unroll
            for (int mt = 0; mt < 4; ++mt) {
                f16x8 a = ldA(wh + OW3T / 2 + (mt * 16 + c) * 72 + kt * 32 + g * 8);
#pragma unroll
                for (int nt = 0; nt < 4; ++nt) acc3[mt][nt] = MF(a, bf[nt], acc3[mt][nt]);
            }
#pragma unroll
            for (int mt = 0; mt < 2; ++mt) {
                f16x8 a = ldA(wh + OW3GT / 2 + (mt * 16 + c) * 72 + kt * 32 + g * 8);
#pragma unroll
                for (int nt = 0; nt < 4; ++nt) acc4[mt][nt] = MF(a, bf[nt], acc4[mt][nt]);
            }
        }

        // ---- GCN tail: DPP mix -> pi-permuted Wg2 MFMA -> DPP mix -> store ----
#pragma unroll
        for (int nt = 0; nt < 4; ++nt) {
            float gv[2][4];
#pragma unroll
            for (int m = 0; m < 2; ++m)
#pragma unroll
                for (int r = 0; r < 4; ++r) {
                    float v = acc4[m][nt][r];
                    float s = bg1v[m][r];
                    s = fmaf(arow.x, qb<0>(v), s);
                    s = fmaf(arow.y, qb<1>(v), s);
                    s = fmaf(arow.z, qb<2>(v), s);
                    s = fmaf(arow.w, qb<3>(v), s);
                    gv[m][r] = fmaxf(s, 0.f);       // g = relu(A.tt + bg1)
                }
            f16x8 bfg = bcat(pkf16(gv[0][0], gv[0][1]), pkf16(gv[0][2], gv[0][3]),
                             pkf16(gv[1][0], gv[1][1]), pkf16(gv[1][2], gv[1][3]));
            f32x4 z = {0.f, 0.f, 0.f, 0.f};
            f32x4 u4 = MF(aWg2, bfg, z);            // u[o][node] on g=0 rows
            float ov[4];
#pragma unroll
            for (int o = 0; o < 4; ++o) {           // out = A.u + bg2
                float s = bg2v[o];
                s = fmaf(arow.x, qb<0>(u4[o]), s);
                s = fmaf(arow.y, qb<1>(u4[o]), s);
                s = fmaf(arow.z, qb<2>(u4[o]), s);
                s = fmaf(arow.w, qb<3>(u4[o]), s);
                ov[o] = s;
            }
            if (g0) {
                f32x4 t; t.x = ov[0]; t.y = ov[1]; t.z = ov[2]; t.w = ov[3];
                *(f32x4*)(out_out + (nbase + nt * 16 + c) * 4) = t;
            }
        }

        // ---- emb store via per-wave LDS transpose (R8-verified) ----
#pragma unroll
        for (int nt = 0; nt < 4; ++nt) {
#pragma unroll
            for (int mt = 0; mt < 4; ++mt) {
                int sl = (mt * 4 + g) ^ (c & 7);
                *(f32x4*)(tb + c * 64 + sl * 4) = acc3[mt][nt];
            }
            float* gp = emb_out + (nbase + nt * 16) * 64;
#pragma unroll
            for (int s = 0; s < 4; ++s) {
                int row = s * 4 + g;
                int sl = c ^ (row & 7);
                f32x4 q = *(const f32x4*)(tb + row * 64 + sl * 4);
                *(f32x4*)(gp + s * 256 + lane * 4) = q;
            }
        }
    }
}

// ---------------------------------------------------------------------------
extern "C" void kernel_launch(void* const* d_in, const int* in_sizes, int n_in,
                              void* d_out, int out_size, void* d_ws, size_t ws_size,
                              hipStream_t stream) {
    const float* x   = (const float*)d_in[0];
    const float* W1  = (const float*)d_in[1];
    const float* b1  = (const float*)d_in[2];
    const float* W2  = (const float*)d_in[3];
    const float* b2  = (const float*)d_in[4];
    const float* W3  = (const float*)d_in[5];
    const float* b3  = (const float*)d_in[6];
    const float* Wg1 = (const float*)d_in[7];
    const float* bg1 = (const float*)d_in[8];
    const float* Wg2 = (const float*)d_in[9];
    const float* bg2 = (const float*)d_in[10];

    unsigned int* mask_arr = (unsigned int*)d_ws;          // 4096 words, all rewritten
    char* img = (char*)d_ws + 16640;                       // past mask array, 256-aligned

    float* emb_out = (float*)d_out;
    float* out_out = emb_out + EMB_ELEMS;

    adj_kernel<<<ADJ_BLOCKS, 256, 0, stream>>>(x, mask_arr);
    prep_kernel<<<4, 256, 0, stream>>>(W1, b1, W2, b2, W3, b3, Wg1, bg1, Wg2, bg2,
                                       mask_arr, img);
    mlp_gcn_mfma<<<NNODE / 1024, 512, 0, stream>>>(x, img, emb_out, out_out);
}

// Round 14
// 108.490 us; speedup vs baseline: 2.6063x; 1.0303x over previous
//
#include <hip/hip_runtime.h>

#define NB 262144
#define NNODE (NB * 4)
#define EMB_ELEMS ((size_t)NNODE * 64)
#define ADJ_BLOCKS (NNODE / 256)               // 4096

typedef __attribute__((ext_vector_type(8))) _Float16 f16x8;
typedef __attribute__((ext_vector_type(4))) float f32x4;
typedef __attribute__((ext_vector_type(4))) unsigned int u32x4;

// ---- weight-image layout (bytes), strides padded to 16B multiples ----
#define OW1E  0        // [128][40] f16 : W1^T ext (k0..3=W1, k4=b1, pad 0)
#define OW2T  10240    // [64][136] f16 : W2^T, k-cols PERMUTED by pi
#define OW3T  27648    // [64][72]  f16 : W3^T, k-cols PERMUTED by pi
#define OW3GT 36864    // [32][72]  f16 : (W3@Wg1)^T, k-cols PERMUTED by pi
#define OWG2A 41472    // [16][40]  f16 : Wg2^T pi-permuted A-tile (rows 4..15 = 0)
#define OF32  42752    // f32 section
#define IMG_BYTES 43600
// f32 section offsets (floats)
#define FB2   0
#define FB3   64
#define FB3G  128
#define FBG1  160
#define FBG2  192
#define FAHAT 196      // [4][4]

#define NWAVE 8                                 // 512 threads
#define WBUF_BYTES 4096                         // per-wave transpose buffer (uses 2304B)
#define SMEM_BYTES (IMG_BYTES + NWAVE * WBUF_BYTES)  // 76368 -> 2 blk/CU needs VGPR<=128

// pi: k-permutation making MFMA C-frags directly consumable as B-frags
// (validated end-to-end R11/R12/R13).
__device__ __forceinline__ int kperm(int ji) {
    int kt = ji >> 5, r = ji & 31, g = r >> 3, e = r & 7;
    return kt * 32 + ((e >> 2) << 4) + (g << 2) + (e & 3);
}

template <int J>
__device__ __forceinline__ float qb(float v) {      // broadcast quad-lane J (DPP)
    constexpr int ctrl = J | (J << 2) | (J << 4) | (J << 6);
    int r = __builtin_amdgcn_update_dpp(0, __builtin_bit_cast(int, v), ctrl, 0xF, 0xF, true);
    return __builtin_bit_cast(float, r);
}

// ---------------------------------------------------------------------------
// Kernel 1: adjacency union (R8-validated).
// ---------------------------------------------------------------------------
__global__ __launch_bounds__(256) void adj_kernel(const float* __restrict__ x,
                                                  unsigned int* __restrict__ mask_arr) {
    __shared__ unsigned int smask;
    if (threadIdx.x == 0) smask = 0u;
    __syncthreads();

    const int t = blockIdx.x * 256 + threadIdx.x;
    const int c = t & 3;
    f32x4 v = *(const f32x4*)(x + (size_t)t * 4);
    float nn = sqrtf(v.x * v.x + v.y * v.y + v.z * v.z + v.w * v.w);
    float inv = 1.0f / fmaxf(nn, 1e-8f);

    unsigned int m = 0u;
#define DOTJ(J) do {                                                            \
        const float bx = qb<J>(v.x), by = qb<J>(v.y);                           \
        const float bz = qb<J>(v.z), bw = qb<J>(v.w);                           \
        const float bi = qb<J>(inv);                                            \
        const float d = v.x * bx + v.y * by + v.z * bz + v.w * bw;              \
        if ((int)((J) != c) & (int)(d * inv * bi > 0.5f)) {                     \
            const int i_ = c < (J) ? c : (J);                                   \
            const int j_ = c < (J) ? (J) : c;                                   \
            m |= 1u << (2 * i_ + j_ - 1 - (i_ >> 1));                           \
        }                                                                       \
    } while (0)
    DOTJ(0); DOTJ(1); DOTJ(2); DOTJ(3);
#undef DOTJ

    if (m) atomicOr(&smask, m);
    __syncthreads();
    if (threadIdx.x == 0) mask_arr[blockIdx.x] = smask;
}

// ---------------------------------------------------------------------------
// Kernel 2: build f16 weight image (k-permuted) + f32 consts. 4 blocks.
// ---------------------------------------------------------------------------
__global__ __launch_bounds__(256) void prep_kernel(
    const float* __restrict__ W1, const float* __restrict__ b1,
    const float* __restrict__ W2, const float* __restrict__ b2,
    const float* __restrict__ W3, const float* __restrict__ b3,
    const float* __restrict__ Wg1, const float* __restrict__ bg1,
    const float* __restrict__ Wg2, const float* __restrict__ bg2,
    const unsigned int* __restrict__ mask_arr, char* __restrict__ img)
{
    const int t = threadIdx.x;
    const int bid = blockIdx.x;
    _Float16* H = (_Float16*)img;
    float* F = (float*)(img + OF32);

    if (bid == 0) {
        __shared__ unsigned red[256];
        unsigned um = 0u;
        for (int i = t; i < ADJ_BLOCKS; i += 256) um |= mask_arr[i];
        red[t] = um;
        __syncthreads();
        for (int s = 128; s > 0; s >>= 1) {
            if (t < s) red[t] |= red[t + s];
            __syncthreads();
        }
        const unsigned m = red[0];

        for (int i = t; i < 64; i += 256) F[FB2 + i] = b2[i];
        for (int i = t; i < 64; i += 256) F[FB3 + i] = b3[i];
        for (int i = t; i < 32; i += 256) {
            float s = 0.f;
            for (int h = 0; h < 64; ++h) s = fmaf(b3[h], Wg1[h * 32 + i], s);
            F[FB3G + i] = s;
        }
        for (int i = t; i < 32; i += 256) F[FBG1 + i] = bg1[i];
        for (int i = t; i < 4; i += 256) F[FBG2 + i] = bg2[i];
        for (int i = t; i < 16 * 40; i += 256) {            // OWG2A: Wg2^T pi-perm
            int o = i / 40, ji = i % 40;
            float v = (o < 4 && ji < 32) ? Wg2[kperm(ji) * 4 + o] : 0.f;
            H[OWG2A / 2 + i] = (_Float16)v;
        }
        if (t == 0) {
            float A[4][4];
            for (int i = 0; i < 4; ++i)
                for (int j = 0; j < 4; ++j) A[i][j] = (i == j) ? 1.f : 0.f;
            int bit = 0;
            for (int i = 0; i < 4; ++i)
                for (int j = i + 1; j < 4; ++j) {
                    if ((m >> bit) & 1u) { A[i][j] = 1.f; A[j][i] = 1.f; }
                    ++bit;
                }
            float dinv[4];
            for (int i = 0; i < 4; ++i)
                dinv[i] = 1.0f / sqrtf(A[i][0] + A[i][1] + A[i][2] + A[i][3]);
            for (int i = 0; i < 4; ++i)
                for (int j = 0; j < 4; ++j) F[FAHAT + i * 4 + j] = dinv[i] * A[i][j] * dinv[j];
        }
    } else if (bid == 1) {
        for (int i = t; i < 128 * 40; i += 256) {           // W1E (k identity)
            int j = i / 40, kk = i % 40;
            float v = (kk < 4) ? W1[kk * 128 + j] : (kk == 4 ? b1[j] : 0.f);
            H[OW1E / 2 + i] = (_Float16)v;
        }
    } else if (bid == 2) {
        for (int i = t; i < 64 * 136; i += 256) {           // W2T, k-cols pi-perm
            int jo = i / 136, ji = i % 136;
            float v = 0.f;
            if (ji < 128) v = W2[kperm(ji) * 64 + jo];
            H[OW2T / 2 + i] = (_Float16)v;
        }
    } else {
        for (int i = t; i < 64 * 72; i += 256) {            // W3T, k-cols pi-perm
            int h = i / 72, j = i % 72;
            float v = 0.f;
            if (j < 64) v = W3[kperm(j) * 64 + h];
            H[OW3T / 2 + i] = (_Float16)v;
        }
        for (int i = t; i < 32 * 72; i += 256) {            // W3GT, k-cols pi-perm
            int e = i / 72, j = i % 72;
            float s = 0.f;
            if (j < 64) {
                const int jj = kperm(j);
                for (int h = 0; h < 64; ++h) s = fmaf(W3[jj * 64 + h], Wg1[h * 32 + e], s);
            }
            H[OW3GT / 2 + i] = (_Float16)s;
        }
    }
}

// ---------------------------------------------------------------------------
// helpers
// ---------------------------------------------------------------------------
__device__ __forceinline__ unsigned pkf16(float a, float b) {
    unsigned short ha = __builtin_bit_cast(unsigned short, (_Float16)a);
    unsigned short hb = __builtin_bit_cast(unsigned short, (_Float16)b);
    return (unsigned)ha | ((unsigned)hb << 16);
}
__device__ __forceinline__ f32x4 MF(f16x8 a, f16x8 b, f32x4 c) {
    return __builtin_amdgcn_mfma_f32_16x16x32_f16(a, b, c, 0, 0, 0);
}
__device__ __forceinline__ f16x8 ldA(const _Float16* p) {
    return *(const f16x8*)p;            // 16B-aligned ds_read_b128
}
__device__ __forceinline__ f16x8 bcat(unsigned X0, unsigned X1,
                                      unsigned Y0, unsigned Y1) {
    u32x4 t; t.x = X0; t.y = X1; t.z = Y0; t.w = Y1;
    return __builtin_bit_cast(f16x8, t);
}

// ---------------------------------------------------------------------------
// Kernel 3: fused MLP+GCN, f16 MFMA. 512 thr = 8 waves, 4 tiles/wave,
// grid 512 = exactly 2 blocks/CU x 256 (single resident round).
// R14: REGISTER-PRESSURE restructure. R5-R13 likely ran at 2 waves/SIMD
// because phase-B live set (acc3 64 + acc4 32 + pk2a 32 + consts) > 128
// VGPRs (m69: >128 regs -> occupancy halves) — explaining the R7/R8/R13
// structural nulls. Now: (a) tail (acc4+out) runs first, its consts loaded
// per-tile; (b) emb computed in two mt-halves (acc3h[2][4]=32 regs), each
// half-row = 128B = ONE full line per node -> still RFO-free stores;
// (c) bf aliases pk2a. Peak live ~100-120 regs -> 4 waves/SIMD.
// ---------------------------------------------------------------------------
__global__ __launch_bounds__(512, 2) void mlp_gcn_mfma(
    const float* __restrict__ x, const char* __restrict__ img,
    float* __restrict__ emb_out, float* __restrict__ out_out)
{
    __shared__ u32x4 smem4[SMEM_BYTES / 16];
    char* smem = (char*)smem4;
    const int tx = threadIdx.x;
    {   // stage weight image (flat, coalesced)
        const u32x4* src = (const u32x4*)img;
        u32x4* dst = (u32x4*)smem;
        for (int i = tx; i < IMG_BYTES / 16; i += 512) dst[i] = src[i];
    }
    __syncthreads();

    const _Float16* wh = (const _Float16*)smem;
    const float* wf = (const float*)(smem + OF32);

    const int wid = tx >> 6, lane = tx & 63;
    const int g = lane >> 4, c = lane & 15;
    const bool g0 = (g == 0);

    float* tb = (float*)(smem + IMG_BYTES) + wid * 1024;   // per-wave buffer

    const size_t nbase0 = ((size_t)blockIdx.x * NWAVE + wid) * 256;  // 4 tiles/wave

#pragma unroll 1
    for (int it = 0; it < 4; ++it) {
        const size_t nbase = nbase0 + (size_t)it * 64;

        // ---- xB frags via direct global loads (R13-validated) ----
        f16x8 xB[4];
#pragma unroll
        for (int nt = 0; nt < 4; ++nt) {
            f32x4 xq = *(const f32x4*)(x + (nbase + nt * 16 + c) * 4);
            u32x4 t;
            t.x = g0 ? pkf16(xq.x, xq.y) : 0u;
            t.y = g0 ? pkf16(xq.z, xq.w) : 0u;
            t.z = g0 ? 0x00003C00u : 0u;    // f16 {1.0, 0}
            t.w = 0u;
            xB[nt] = __builtin_bit_cast(f16x8, t);
        }

        // ---- L1+L2 per kt: h1 chunk -> bcat B-frags -> L2 MFMAs ----
        f32x4 acc2[4][4];
#pragma unroll
        for (int mt = 0; mt < 4; ++mt) {
            f32x4 bv = *(const f32x4*)(wf + FB2 + mt * 16 + g * 4);
#pragma unroll
            for (int nt = 0; nt < 4; ++nt) acc2[mt][nt] = bv;
        }
#pragma unroll
        for (int kt = 0; kt < 4; ++kt) {
            f16x8 a0 = ldA(wh + OW1E / 2 + ((2 * kt + 0) * 16 + c) * 40 + g * 8);
            f16x8 a1 = ldA(wh + OW1E / 2 + ((2 * kt + 1) * 16 + c) * 40 + g * 8);
            f16x8 bf[4];
#pragma unroll
            for (int nt = 0; nt < 4; ++nt) {
                f32x4 z = {0.f, 0.f, 0.f, 0.f};
                f32x4 t0 = MF(a0, xB[nt], z);
                f32x4 t1 = MF(a1, xB[nt], z);
                bf[nt] = bcat(pkf16(fmaxf(t0[0], 0.f), fmaxf(t0[1], 0.f)),
                              pkf16(fmaxf(t0[2], 0.f), fmaxf(t0[3], 0.f)),
                              pkf16(fmaxf(t1[0], 0.f), fmaxf(t1[1], 0.f)),
                              pkf16(fmaxf(t1[2], 0.f), fmaxf(t1[3], 0.f)));
            }
#pragma unroll
            for (int mt = 0; mt < 4; ++mt) {
                f16x8 a = ldA(wh + OW2T / 2 + (mt * 16 + c) * 136 + kt * 32 + g * 8);
#pragma unroll
                for (int nt = 0; nt < 4; ++nt) acc2[mt][nt] = MF(a, bf[nt], acc2[mt][nt]);
            }
        }

        // ---- pack h2 (relu); acc2 dies here ----
        unsigned pk2a[4][4][2];
#pragma unroll
        for (int mt = 0; mt < 4; ++mt)
#pragma unroll
            for (int nt = 0; nt < 4; ++nt) {
                pk2a[mt][nt][0] = pkf16(fmaxf(acc2[mt][nt][0], 0.f), fmaxf(acc2[mt][nt][1], 0.f));
                pk2a[mt][nt][1] = pkf16(fmaxf(acc2[mt][nt][2], 0.f), fmaxf(acc2[mt][nt][3], 0.f));
            }

        // ---- tail FIRST: acc4 (tt) + GCN mix + out store; consts per-tile ----
        {
            f32x4 acc4[2][4];
#pragma unroll
            for (int mt = 0; mt < 2; ++mt) {
                f32x4 bv = *(const f32x4*)(wf + FB3G + mt * 16 + g * 4);
#pragma unroll
                for (int nt = 0; nt < 4; ++nt) acc4[mt][nt] = bv;
            }
#pragma unroll
            for (int kt = 0; kt < 2; ++kt) {
#pragma unroll
                for (int mt = 0; mt < 2; ++mt) {
                    f16x8 a = ldA(wh + OW3GT / 2 + (mt * 16 + c) * 72 + kt * 32 + g * 8);
#pragma unroll
                    for (int nt = 0; nt < 4; ++nt) {
                        f16x8 bf = bcat(pk2a[2 * kt][nt][0], pk2a[2 * kt][nt][1],
                                        pk2a[2 * kt + 1][nt][0], pk2a[2 * kt + 1][nt][1]);
                        acc4[mt][nt] = MF(a, bf, acc4[mt][nt]);
                    }
                }
            }
            const f32x4 arow = *(const f32x4*)(wf + FAHAT + (c & 3) * 4);
            f32x4 bg1v[2];
            bg1v[0] = *(const f32x4*)(wf + FBG1 + g * 4);
            bg1v[1] = *(const f32x4*)(wf + FBG1 + 16 + g * 4);
            const f32x4 bg2v = *(const f32x4*)(wf + FBG2);
            const f16x8 aWg2 = ldA(wh + OWG2A / 2 + c * 40 + g * 8);
#pragma unroll
            for (int nt = 0; nt < 4; ++nt) {
                float gv[2][4];
#pragma unroll
                for (int m = 0; m < 2; ++m)
#pragma unroll
                    for (int r = 0; r < 4; ++r) {
                        float v = acc4[m][nt][r];
                        float s = bg1v[m][r];
                        s = fmaf(arow.x, qb<0>(v), s);
                        s = fmaf(arow.y, qb<1>(v), s);
                        s = fmaf(arow.z, qb<2>(v), s);
                        s = fmaf(arow.w, qb<3>(v), s);
                        gv[m][r] = fmaxf(s, 0.f);
                    }
                f16x8 bfg = bcat(pkf16(gv[0][0], gv[0][1]), pkf16(gv[0][2], gv[0][3]),
                                 pkf16(gv[1][0], gv[1][1]), pkf16(gv[1][2], gv[1][3]));
                f32x4 z = {0.f, 0.f, 0.f, 0.f};
                f32x4 u4 = MF(aWg2, bfg, z);
                float ov[4];
#pragma unroll
                for (int o = 0; o < 4; ++o) {
                    float s = bg2v[o];
                    s = fmaf(arow.x, qb<0>(u4[o]), s);
                    s = fmaf(arow.y, qb<1>(u4[o]), s);
                    s = fmaf(arow.z, qb<2>(u4[o]), s);
                    s = fmaf(arow.w, qb<3>(u4[o]), s);
                    ov[o] = s;
                }
                if (g0) {
                    f32x4 t; t.x = ov[0]; t.y = ov[1]; t.z = ov[2]; t.w = ov[3];
                    *(f32x4*)(out_out + (nbase + nt * 16 + c) * 4) = t;
                }
            }
        }

        // ---- emb in two mt-halves: acc3h[2][4] only (32 regs) ----
#pragma unroll 1
        for (int mh = 0; mh < 2; ++mh) {
            f32x4 acc3h[2][4];
#pragma unroll
            for (int mt2 = 0; mt2 < 2; ++mt2) {
                f32x4 bv = *(const f32x4*)(wf + FB3 + (mh * 2 + mt2) * 16 + g * 4);
#pragma unroll
                for (int nt = 0; nt < 4; ++nt) acc3h[mt2][nt] = bv;
            }
#pragma unroll
            for (int kt = 0; kt < 2; ++kt) {
#pragma unroll
                for (int mt2 = 0; mt2 < 2; ++mt2) {
                    const int mt = mh * 2 + mt2;
                    f16x8 a = ldA(wh + OW3T / 2 + (mt * 16 + c) * 72 + kt * 32 + g * 8);
#pragma unroll
                    for (int nt = 0; nt < 4; ++nt) {
                        f16x8 bf = bcat(pk2a[2 * kt][nt][0], pk2a[2 * kt][nt][1],
                                        pk2a[2 * kt + 1][nt][0], pk2a[2 * kt + 1][nt][1]);
                        acc3h[mt2][nt] = MF(a, bf, acc3h[mt2][nt]);
                    }
                }
            }
            // per nt: transpose half-rows via tb (stride 36 pads banks; XOR
            // swizzle bijective in [0,8)); store = 16 nodes x 128B FULL LINES.
#pragma unroll
            for (int nt = 0; nt < 4; ++nt) {
#pragma unroll
                for (int mt2 = 0; mt2 < 2; ++mt2) {
                    int sl = (mt2 * 4 + g) ^ (c & 7);
                    *(f32x4*)(tb + c * 36 + sl * 4) = acc3h[mt2][nt];
                }
                float* gp = emb_out + (nbase + nt * 16) * 64 + mh * 32;
#pragma unroll
                for (int s = 0; s < 2; ++s) {
                    int F = s * 64 + lane;
                    int node = F >> 3, col4 = F & 7;
                    int sl = col4 ^ (node & 7);
                    f32x4 q = *(const f32x4*)(tb + node * 36 + sl * 4);
                    *(f32x4*)(gp + node * 64 + col4 * 4) = q;
                }
            }
        }
    }
}

// ---------------------------------------------------------------------------
extern "C" void kernel_launch(void* const* d_in, const int* in_sizes, int n_in,
                              void* d_out, int out_size, void* d_ws, size_t ws_size,
                              hipStream_t stream) {
    const float* x   = (const float*)d_in[0];
    const float* W1  = (const float*)d_in[1];
    const float* b1  = (const float*)d_in[2];
    const float* W2  = (const float*)d_in[3];
    const float* b2  = (const float*)d_in[4];
    const float* W3  = (const float*)d_in[5];
    const float* b3  = (const float*)d_in[6];
    const float* Wg1 = (const float*)d_in[7];
    const float* bg1 = (const float*)d_in[8];
    const float* Wg2 = (const float*)d_in[9];
    const float* bg2 = (const float*)d_in[10];

    unsigned int* mask_arr = (unsigned int*)d_ws;          // 4096 words, all rewritten
    char* img = (char*)d_ws + 16640;                       // past mask array, 256-aligned

    float* emb_out = (float*)d_out;
    float* out_out = emb_out + EMB_ELEMS;

    adj_kernel<<<ADJ_BLOCKS, 256, 0, stream>>>(x, mask_arr);
    prep_kernel<<<4, 256, 0, stream>>>(W1, b1, W2, b2, W3, b3, Wg1, bg1, Wg2, bg2,
                                       mask_arr, img);
    mlp_gcn_mfma<<<NNODE / 2048, 512, 0, stream>>>(x, img, emb_out, out_out);
}